// Round 1
// baseline (1770.002 us; speedup 1.0000x reference)
//
#include <hip/hip_runtime.h>
#include <math.h>

#define L_DIM 2048
#define N_DIM 8
#define E_DIM 1024
#define H_DIM 16
#define D_DIM 64
#define M_DIM (L_DIM * N_DIM)     // 16384
#define NHEADS (N_DIM * H_DIM)    // 128
#define TWO_D 128
#define CH 8                      // L-chunks for kv partial reduction
#define LCH (L_DIM / CH)          // 256

// ---------------------------------------------------------------------------
// GEMM-NT: C[m,n] = act( sum_k A[m,k] * W[n,k] ), A:(16384,1024), W:(1024,1024)
// 128x128 tile, BK=16, 256 threads, 8x8 micro-tile. fp32 vector.
// ---------------------------------------------------------------------------
template <int RELU>
__global__ __launch_bounds__(256) void gemm_nt(const float* __restrict__ A,
                                               const float* __restrict__ W,
                                               float* __restrict__ C) {
    __shared__ float As[16][132];
    __shared__ float Bs[16][132];
    const int t = threadIdx.x;
    const int m0 = blockIdx.y * 128;
    const int n0 = blockIdx.x * 128;

    const int my = t >> 4;        // 0..15 -> m micro row * 8
    const int nx = t & 15;        // 0..15 -> n micro col * 8
    const int r0 = t >> 2;        // 0..63 load row
    const int c4 = (t & 3) * 4;   // 0,4,8,12 load col (k)

    float acc[8][8];
#pragma unroll
    for (int i = 0; i < 8; ++i)
#pragma unroll
        for (int j = 0; j < 8; ++j) acc[i][j] = 0.0f;

    for (int k0 = 0; k0 < E_DIM; k0 += 16) {
#pragma unroll
        for (int half = 0; half < 2; ++half) {
            const int r = r0 + half * 64;
            float4 av = *(const float4*)&A[(size_t)(m0 + r) * E_DIM + k0 + c4];
            float4 bv = *(const float4*)&W[(size_t)(n0 + r) * E_DIM + k0 + c4];
            As[c4 + 0][r] = av.x; As[c4 + 1][r] = av.y;
            As[c4 + 2][r] = av.z; As[c4 + 3][r] = av.w;
            Bs[c4 + 0][r] = bv.x; Bs[c4 + 1][r] = bv.y;
            Bs[c4 + 2][r] = bv.z; Bs[c4 + 3][r] = bv.w;
        }
        __syncthreads();
#pragma unroll
        for (int kk = 0; kk < 16; ++kk) {
            float a[8], b[8];
            *(float4*)&a[0] = *(float4*)&As[kk][my * 8];
            *(float4*)&a[4] = *(float4*)&As[kk][my * 8 + 4];
            *(float4*)&b[0] = *(float4*)&Bs[kk][nx * 8];
            *(float4*)&b[4] = *(float4*)&Bs[kk][nx * 8 + 4];
#pragma unroll
            for (int i = 0; i < 8; ++i)
#pragma unroll
                for (int j = 0; j < 8; ++j) acc[i][j] = fmaf(a[i], b[j], acc[i][j]);
        }
        __syncthreads();
    }

#pragma unroll
    for (int r = 0; r < 8; ++r) {
        const int m = m0 + my * 8 + r;
        float4 o0 = make_float4(acc[r][0], acc[r][1], acc[r][2], acc[r][3]);
        float4 o1 = make_float4(acc[r][4], acc[r][5], acc[r][6], acc[r][7]);
        if (RELU) {
            o0.x = fmaxf(o0.x, 0.f); o0.y = fmaxf(o0.y, 0.f);
            o0.z = fmaxf(o0.z, 0.f); o0.w = fmaxf(o0.w, 0.f);
            o1.x = fmaxf(o1.x, 0.f); o1.y = fmaxf(o1.y, 0.f);
            o1.z = fmaxf(o1.z, 0.f); o1.w = fmaxf(o1.w, 0.f);
        }
        *(float4*)&C[(size_t)m * E_DIM + n0 + nx * 8] = o0;
        *(float4*)&C[(size_t)m * E_DIM + n0 + nx * 8 + 4] = o1;
    }
}

// ---------------------------------------------------------------------------
// kv partial: per (head g, chunk c): S/C outer-product sums over 256 l's.
// kvp[c][g][i][j], i in [0,128) (0..63 sin-part, 64..127 cos-part), j in [0,64)
// ksp[c][g][i] = partial k_ column sums.
// ---------------------------------------------------------------------------
__global__ __launch_bounds__(256) void kv_partial(const float* __restrict__ Kb,
                                                  const float* __restrict__ Vb,
                                                  float* __restrict__ kvp,
                                                  float* __restrict__ ksp) {
    const int g = blockIdx.x;  // head 0..127
    const int c = blockIdx.y;  // chunk 0..7
    const int nb = g >> 4, hh = g & 15;
    const int t = threadIdx.x;

    __shared__ float Kt[32][64];
    __shared__ float Vt[32][64];
    __shared__ float sT[32], cT[32];

    const int gi = t >> 3;      // 0..31 -> i0 = 2*gi
    const int gj = t & 7;       // 0..7  -> j0 = 8*gj
    const int i0 = gi * 2, j0 = gj * 8;
    const int baseCol = hh * 64;

    float S[2][8], Cc[2][8];
#pragma unroll
    for (int i = 0; i < 2; ++i)
#pragma unroll
        for (int j = 0; j < 8; ++j) { S[i][j] = 0.f; Cc[i][j] = 0.f; }
    float sk[2] = {0.f, 0.f}, ck[2] = {0.f, 0.f};

    for (int lt = 0; lt < LCH; lt += 32) {
        const int lbase = c * LCH + lt;
        for (int s = t; s < 512; s += 256) {
            const int lr = s >> 4;
            const int cc = (s & 15) * 4;
            const size_t gaddr = (size_t)((lbase + lr) * N_DIM + nb) * E_DIM + baseCol + cc;
            *(float4*)&Kt[lr][cc] = *(const float4*)&Kb[gaddr];
            *(float4*)&Vt[lr][cc] = *(const float4*)&Vb[gaddr];
        }
        if (t < 32) {
            const float ang = 1.57079632679489662f * (float)(lbase + t + 1) / (float)L_DIM;
            sT[t] = sinf(ang);
            cT[t] = cosf(ang);
        }
        __syncthreads();
#pragma unroll 4
        for (int lr = 0; lr < 32; ++lr) {
            const float sl = sT[lr], cl = cT[lr];
            const float k0v = Kt[lr][i0], k1v = Kt[lr][i0 + 1];
            const float ks0 = k0v * sl, ks1 = k1v * sl;
            const float kc0 = k0v * cl, kc1 = k1v * cl;
            sk[0] += ks0; sk[1] += ks1; ck[0] += kc0; ck[1] += kc1;
            float v8[8];
            *(float4*)&v8[0] = *(float4*)&Vt[lr][j0];
            *(float4*)&v8[4] = *(float4*)&Vt[lr][j0 + 4];
#pragma unroll
            for (int j = 0; j < 8; ++j) {
                S[0][j] = fmaf(ks0, v8[j], S[0][j]);
                S[1][j] = fmaf(ks1, v8[j], S[1][j]);
                Cc[0][j] = fmaf(kc0, v8[j], Cc[0][j]);
                Cc[1][j] = fmaf(kc1, v8[j], Cc[1][j]);
            }
        }
        __syncthreads();
    }

    float* outp = kvp + ((size_t)(c * NHEADS + g) * TWO_D) * D_DIM;
#pragma unroll
    for (int ii = 0; ii < 2; ++ii) {
        *(float4*)&outp[(size_t)(i0 + ii) * D_DIM + j0] =
            make_float4(S[ii][0], S[ii][1], S[ii][2], S[ii][3]);
        *(float4*)&outp[(size_t)(i0 + ii) * D_DIM + j0 + 4] =
            make_float4(S[ii][4], S[ii][5], S[ii][6], S[ii][7]);
        *(float4*)&outp[(size_t)(64 + i0 + ii) * D_DIM + j0] =
            make_float4(Cc[ii][0], Cc[ii][1], Cc[ii][2], Cc[ii][3]);
        *(float4*)&outp[(size_t)(64 + i0 + ii) * D_DIM + j0 + 4] =
            make_float4(Cc[ii][4], Cc[ii][5], Cc[ii][6], Cc[ii][7]);
    }
    if (gj == 0) {
        float* ksb = ksp + (size_t)(c * NHEADS + g) * TWO_D;
        ksb[i0] = sk[0];
        ksb[i0 + 1] = sk[1];
        ksb[64 + i0] = ck[0];
        ksb[64 + i0 + 1] = ck[1];
    }
}

// ---------------------------------------------------------------------------
// reduce partials over chunks
// ---------------------------------------------------------------------------
__global__ __launch_bounds__(256) void reduce_kv(const float* __restrict__ kvp,
                                                 const float* __restrict__ ksp,
                                                 float* __restrict__ kv,
                                                 float* __restrict__ ksum) {
    const int idx = blockIdx.x * 256 + threadIdx.x;
    const int KVN = NHEADS * TWO_D * D_DIM;  // 1048576
    const int KSN = NHEADS * TWO_D;          // 16384
    if (idx < KVN) {
        float s = 0.f;
#pragma unroll
        for (int c = 0; c < CH; ++c) s += kvp[(size_t)c * KVN + idx];
        kv[idx] = s;
    } else if (idx < KVN + KSN) {
        const int j = idx - KVN;
        float s = 0.f;
#pragma unroll
        for (int c = 0; c < CH; ++c) s += ksp[(size_t)c * KSN + j];
        ksum[j] = s;
    }
}

// ---------------------------------------------------------------------------
// attn: per (head g, l-tile of 64): z then attn = z * q_ @ kv, written in
// (L, N, E) layout for the final GEMM.
// ---------------------------------------------------------------------------
__global__ __launch_bounds__(256) void attn_kernel(const float* __restrict__ Q,
                                                   const float* __restrict__ kv,
                                                   const float* __restrict__ ksum,
                                                   float* __restrict__ attnOut) {
    const int g = blockIdx.x;   // head
    const int lt = blockIdx.y;  // l-tile (64 rows)
    const int nb = g >> 4, hh = g & 15;
    const int t = threadIdx.x;

    __shared__ float kvs[TWO_D][64];  // 32 KB
    __shared__ float qT[TWO_D][64];   // q_^T [i][l], 32 KB
    __shared__ float sTab[64], cTab[64], ksS[TWO_D], pz[64][4], zs[64];

    // stage kv (head slice) and ksum
    {
        const float4* kv4 = (const float4*)(kv + (size_t)g * TWO_D * D_DIM);
        float4* kvs4 = (float4*)&kvs[0][0];
        for (int s = t; s < TWO_D * D_DIM / 4; s += 256) kvs4[s] = kv4[s];
    }
    if (t < TWO_D) ksS[t] = ksum[(size_t)g * TWO_D + t];

    const int lbase = lt * 64;
    if (t < 64) {
        const float ang = 1.57079632679489662f * (float)(lbase + t + 1) / (float)L_DIM;
        sTab[t] = sinf(ang);
        cTab[t] = cosf(ang);
    }

    // load q rows: thread t -> l = t>>2, dd block = (t&3)*16
    const int lq = t >> 2;
    const int dq = (t & 3) * 16;
    float qv[16];
    {
        const float* qrow = Q + (size_t)((lbase + lq) * N_DIM + nb) * E_DIM + hh * 64 + dq;
        *(float4*)&qv[0]  = *(const float4*)&qrow[0];
        *(float4*)&qv[4]  = *(const float4*)&qrow[4];
        *(float4*)&qv[8]  = *(const float4*)&qrow[8];
        *(float4*)&qv[12] = *(const float4*)&qrow[12];
    }
    __syncthreads();  // sTab/cTab, kvs, ksS visible

    {
        const float sl = sTab[lq], cl = cTab[lq];
#pragma unroll
        for (int j = 0; j < 16; ++j) {
            qT[dq + j][lq] = qv[j] * sl;
            qT[64 + dq + j][lq] = qv[j] * cl;
        }
    }
    __syncthreads();  // qT ready

    // z: 4 threads per l, each sums 32 i's
    {
        const int lz = t >> 2, qz = t & 3;
        float p = 0.f;
#pragma unroll
        for (int i = 0; i < 32; ++i) p = fmaf(qT[qz * 32 + i][lz], ksS[qz * 32 + i], p);
        pz[lz][qz] = p;
    }
    __syncthreads();
    if (t < 64) {
        const float s = pz[t][0] + pz[t][1] + pz[t][2] + pz[t][3];
        zs[t] = 1.0f / fmaxf(s, 1e-6f);
    }
    __syncthreads();

    // attn tile 64l x 64d, thread = 4l x 4d
    const int ml = (t >> 4) * 4;
    const int nd = (t & 15) * 4;
    float acc[4][4];
#pragma unroll
    for (int i = 0; i < 4; ++i)
#pragma unroll
        for (int j = 0; j < 4; ++j) acc[i][j] = 0.f;

    for (int i = 0; i < TWO_D; ++i) {
        float4 a = *(float4*)&qT[i][ml];
        float4 b = *(float4*)&kvs[i][nd];
        acc[0][0] = fmaf(a.x, b.x, acc[0][0]); acc[0][1] = fmaf(a.x, b.y, acc[0][1]);
        acc[0][2] = fmaf(a.x, b.z, acc[0][2]); acc[0][3] = fmaf(a.x, b.w, acc[0][3]);
        acc[1][0] = fmaf(a.y, b.x, acc[1][0]); acc[1][1] = fmaf(a.y, b.y, acc[1][1]);
        acc[1][2] = fmaf(a.y, b.z, acc[1][2]); acc[1][3] = fmaf(a.y, b.w, acc[1][3]);
        acc[2][0] = fmaf(a.z, b.x, acc[2][0]); acc[2][1] = fmaf(a.z, b.y, acc[2][1]);
        acc[2][2] = fmaf(a.z, b.z, acc[2][2]); acc[2][3] = fmaf(a.z, b.w, acc[2][3]);
        acc[3][0] = fmaf(a.w, b.x, acc[3][0]); acc[3][1] = fmaf(a.w, b.y, acc[3][1]);
        acc[3][2] = fmaf(a.w, b.z, acc[3][2]); acc[3][3] = fmaf(a.w, b.w, acc[3][3]);
    }

#pragma unroll
    for (int r = 0; r < 4; ++r) {
        const float z = zs[ml + r];
        float4 o = make_float4(acc[r][0] * z, acc[r][1] * z, acc[r][2] * z, acc[r][3] * z);
        float* orow = attnOut + (size_t)((lbase + ml + r) * N_DIM + nb) * E_DIM + hh * 64 + nd;
        *(float4*)orow = o;
    }
}

// ---------------------------------------------------------------------------
extern "C" void kernel_launch(void* const* d_in, const int* in_sizes, int n_in,
                              void* d_out, int out_size, void* d_ws, size_t ws_size,
                              hipStream_t stream) {
    const float* X  = (const float*)d_in[0];  // query (L,N,E)
    const float* Wq = (const float*)d_in[1];
    const float* Wk = (const float*)d_in[2];
    const float* Wv = (const float*)d_in[3];
    const float* Wo = (const float*)d_in[4];
    float* out = (float*)d_out;

    char* ws = (char*)d_ws;
    const size_t SZ_MAT = (size_t)M_DIM * E_DIM * sizeof(float);  // 64 MB
    float* buf0 = (float*)(ws);                  // K, later Q
    float* buf1 = (float*)(ws + SZ_MAT);         // V, later attn
    float* kvp  = (float*)(ws + 2 * SZ_MAT);                       // 33.5 MB
    float* ksp  = (float*)(ws + 2 * SZ_MAT + (size_t)CH * NHEADS * TWO_D * D_DIM * 4);
    float* kv   = (float*)((char*)ksp + (size_t)CH * NHEADS * TWO_D * 4);
    float* ksum = (float*)((char*)kv + (size_t)NHEADS * TWO_D * D_DIM * 4);

    dim3 gemmGrid(E_DIM / 128, M_DIM / 128);  // (8, 128)

    // K = relu(X Wk^T), V = X Wv^T
    gemm_nt<1><<<gemmGrid, 256, 0, stream>>>(X, Wk, buf0);
    gemm_nt<0><<<gemmGrid, 256, 0, stream>>>(X, Wv, buf1);

    // kv & ksum
    kv_partial<<<dim3(NHEADS, CH), 256, 0, stream>>>(buf0, buf1, kvp, ksp);
    {
        const int total = NHEADS * TWO_D * D_DIM + NHEADS * TWO_D;
        reduce_kv<<<(total + 255) / 256, 256, 0, stream>>>(kvp, ksp, kv, ksum);
    }

    // Q = relu(X Wq^T) into buf0 (K is dead)
    gemm_nt<1><<<gemmGrid, 256, 0, stream>>>(X, Wq, buf0);

    // attn into buf1 (V is dead)
    attn_kernel<<<dim3(NHEADS, L_DIM / 64), 256, 0, stream>>>(buf0, kv, ksum, buf1);

    // out = attn Wo^T
    gemm_nt<0><<<gemmGrid, 256, 0, stream>>>(buf1, Wo, out);
}

// Round 2
// 743.407 us; speedup vs baseline: 2.3809x; 2.3809x over previous
//
#include <hip/hip_runtime.h>
#include <math.h>

#define L_DIM 2048
#define N_DIM 8
#define E_DIM 1024
#define H_DIM 16
#define D_DIM 64
#define M_DIM (L_DIM * N_DIM)     // 16384
#define NHEADS (N_DIM * H_DIM)    // 128
#define TWO_D 128
#define K_DIM 1024
#define CH 8
#define LCH (L_DIM / CH)          // 256

typedef __attribute__((ext_vector_type(8))) __bf16 bf16x8;
typedef __attribute__((ext_vector_type(4))) float f32x4;

__device__ __forceinline__ ushort f2bf(float x) {
    union { float f; unsigned u; } a; a.f = x;
    unsigned r = a.u + 0x7fffu + ((a.u >> 16) & 1u);
    return (ushort)(r >> 16);
}
__device__ __forceinline__ float bf2f(ushort h) {
    union { unsigned u; float f; } a; a.u = ((unsigned)h) << 16;
    return a.f;
}

__device__ __forceinline__ void gload_lds16(const void* g, void* l) {
    __builtin_amdgcn_global_load_lds((const __attribute__((address_space(1))) void*)g,
                                     (__attribute__((address_space(3))) void*)l, 16, 0, 0);
}

// ---------------------------------------------------------------------------
// split fp32 -> bf16 hi + bf16 lo  (x ~= hi + lo, lo captures next 8 bits)
// ---------------------------------------------------------------------------
__global__ __launch_bounds__(256) void split_fp32(const float* __restrict__ in,
                                                  ushort* __restrict__ hi,
                                                  ushort* __restrict__ lo, int n4) {
    int i = blockIdx.x * 256 + threadIdx.x;
    const int stride = gridDim.x * 256;
    for (; i < n4; i += stride) {
        float4 v = ((const float4*)in)[i];
        ushort h0 = f2bf(v.x), h1 = f2bf(v.y), h2 = f2bf(v.z), h3 = f2bf(v.w);
        ushort l0 = f2bf(v.x - bf2f(h0)), l1 = f2bf(v.y - bf2f(h1));
        ushort l2 = f2bf(v.z - bf2f(h2)), l3 = f2bf(v.w - bf2f(h3));
        ((ushort4*)hi)[i] = make_ushort4(h0, h1, h2, h3);
        ((ushort4*)lo)[i] = make_ushort4(l0, l1, l2, l3);
    }
}

// ---------------------------------------------------------------------------
// split-bf16 MFMA GEMM-NT: C = act(A * W^T), A:(16384,1024), W:(1024,1024)
// A,W given as hi/lo bf16 pairs. 128x128 tile, BK=32, 4 waves, 64x64/wave.
// 3 MFMAs per (m,n,k): hi*hi + hi*lo + lo*hi (lo*lo dropped, ~2^-18).
// ---------------------------------------------------------------------------
__device__ __forceinline__ void compute_step(const ushort (*buf)[128 * 32],
                                             const int* aoff, const int* boff,
                                             f32x4 acc[4][4]) {
    bf16x8 ah[4], al[4], bh[4], bl[4];
#pragma unroll
    for (int m = 0; m < 4; ++m) {
        ah[m] = *(const bf16x8*)&buf[0][aoff[m]];
        al[m] = *(const bf16x8*)&buf[1][aoff[m]];
    }
#pragma unroll
    for (int n = 0; n < 4; ++n) {
        bh[n] = *(const bf16x8*)&buf[2][boff[n]];
        bl[n] = *(const bf16x8*)&buf[3][boff[n]];
    }
#pragma unroll
    for (int m = 0; m < 4; ++m)
#pragma unroll
        for (int n = 0; n < 4; ++n) {
            acc[m][n] = __builtin_amdgcn_mfma_f32_16x16x32_bf16(ah[m], bh[n], acc[m][n], 0, 0, 0);
            acc[m][n] = __builtin_amdgcn_mfma_f32_16x16x32_bf16(ah[m], bl[n], acc[m][n], 0, 0, 0);
            acc[m][n] = __builtin_amdgcn_mfma_f32_16x16x32_bf16(al[m], bh[n], acc[m][n], 0, 0, 0);
        }
}

template <int RELU>
__global__ __launch_bounds__(256) void gemm_split(const ushort* __restrict__ Ahi,
                                                  const ushort* __restrict__ Alo,
                                                  const ushort* __restrict__ Bhi,
                                                  const ushort* __restrict__ Blo,
                                                  float* __restrict__ C) {
    __shared__ ushort smem[2][4][128 * 32];  // [buf][Ahi,Alo,Bhi,Blo] 64 KB

    const int t = threadIdx.x;
    const int wid = t >> 6;
    const int lane = t & 63;

    // XCD-grouped swizzle: XCD c (= blockIdx%8 by round-robin dispatch) gets
    // a contiguous mb range so A-panels stay in one XCD's L2.
    const int x = blockIdx.x;
    const int cxcd = x & 7;
    const int j = x >> 3;
    const int mb = cxcd * 16 + (j >> 3);
    const int nb = j & 7;
    const int m0 = mb * 128, n0 = nb * 128;

    // ---- staging addresses (inverse-swizzled global source, linear LDS) ----
    const int srow = t >> 2;                       // 0..63
    const int sch = t & 3;                         // 16B slot within 64B row
    const int gch = sch ^ ((srow >> 1) & 3);       // global chunk this slot holds
    const ushort* gA0 = Ahi + (size_t)(m0 + srow) * K_DIM + gch * 8;
    const ushort* gL0 = Alo + (size_t)(m0 + srow) * K_DIM + gch * 8;
    const ushort* gB0 = Bhi + (size_t)(n0 + srow) * K_DIM + gch * 8;
    const ushort* gC0 = Blo + (size_t)(n0 + srow) * K_DIM + gch * 8;
    const size_t half = (size_t)64 * K_DIM;        // ((srow+64)>>1)&3 == (srow>>1)&3

#define STAGE(b, koff)                                                        \
    do {                                                                      \
        gload_lds16(gA0 + (koff), &smem[b][0][wid * 512]);                    \
        gload_lds16(gA0 + half + (koff), &smem[b][0][2048 + wid * 512]);      \
        gload_lds16(gL0 + (koff), &smem[b][1][wid * 512]);                    \
        gload_lds16(gL0 + half + (koff), &smem[b][1][2048 + wid * 512]);      \
        gload_lds16(gB0 + (koff), &smem[b][2][wid * 512]);                    \
        gload_lds16(gB0 + half + (koff), &smem[b][2][2048 + wid * 512]);      \
        gload_lds16(gC0 + (koff), &smem[b][3][wid * 512]);                    \
        gload_lds16(gC0 + half + (koff), &smem[b][3][2048 + wid * 512]);      \
    } while (0)

    // ---- fragment read offsets (swizzled) ----
    const int wm = wid >> 1, wn = wid & 1;
    const int lr = lane & 15;
    const int kc = lane >> 4;
    int aoff[4], boff[4];
#pragma unroll
    for (int m = 0; m < 4; ++m) {
        const int r = wm * 64 + m * 16 + lr;
        aoff[m] = r * 32 + ((kc ^ ((r >> 1) & 3)) << 3);
    }
#pragma unroll
    for (int n = 0; n < 4; ++n) {
        const int r = wn * 64 + n * 16 + lr;
        boff[n] = r * 32 + ((kc ^ ((r >> 1) & 3)) << 3);
    }

    f32x4 acc[4][4];
    const f32x4 zv = {0.f, 0.f, 0.f, 0.f};
#pragma unroll
    for (int m = 0; m < 4; ++m)
#pragma unroll
        for (int n = 0; n < 4; ++n) acc[m][n] = zv;

    STAGE(0, 0);
    __syncthreads();
#pragma unroll 1
    for (int kt = 0; kt < 31; ++kt) {
        const int b = kt & 1;
        STAGE(b ^ 1, (size_t)(kt + 1) * 32);
        compute_step(smem[b], aoff, boff, acc);
        __syncthreads();
    }
    compute_step(smem[1], aoff, boff, acc);

    // ---- epilogue: C/D layout col=lane&15, row=(lane>>4)*4+q (m89) ----
    const int erow = (lane >> 4) * 4;
    const int ecol = lane & 15;
#pragma unroll
    for (int m = 0; m < 4; ++m) {
        const int gr = m0 + wm * 64 + m * 16 + erow;
#pragma unroll
        for (int n = 0; n < 4; ++n) {
            const int gc = n0 + wn * 64 + n * 16 + ecol;
            f32x4 v = acc[m][n];
#pragma unroll
            for (int q = 0; q < 4; ++q) {
                float val = v[q];
                if (RELU) val = fmaxf(val, 0.f);
                C[(size_t)(gr + q) * E_DIM + gc] = val;
            }
        }
    }
#undef STAGE
}

// ---------------------------------------------------------------------------
// kv partial sums, atomically accumulated into kv / ksum (zeroed via memset).
// ---------------------------------------------------------------------------
__global__ __launch_bounds__(256) void kv_partial(const float* __restrict__ Kb,
                                                  const float* __restrict__ Vb,
                                                  float* __restrict__ kv,
                                                  float* __restrict__ ksum) {
    const int g = blockIdx.x;  // head 0..127
    const int c = blockIdx.y;  // chunk 0..7
    const int nb = g >> 4, hh = g & 15;
    const int t = threadIdx.x;

    __shared__ float Kt[32][64];
    __shared__ float Vt[32][64];
    __shared__ float sT[32], cT[32];

    const int gi = t >> 3;
    const int gj = t & 7;
    const int i0 = gi * 2, j0 = gj * 8;
    const int baseCol = hh * 64;

    float S[2][8], Cc[2][8];
#pragma unroll
    for (int i = 0; i < 2; ++i)
#pragma unroll
        for (int jj = 0; jj < 8; ++jj) { S[i][jj] = 0.f; Cc[i][jj] = 0.f; }
    float sk[2] = {0.f, 0.f}, ck[2] = {0.f, 0.f};

    for (int lt = 0; lt < LCH; lt += 32) {
        const int lbase = c * LCH + lt;
        for (int s = t; s < 512; s += 256) {
            const int lr = s >> 4;
            const int cc = (s & 15) * 4;
            const size_t gaddr = (size_t)((lbase + lr) * N_DIM + nb) * E_DIM + baseCol + cc;
            *(float4*)&Kt[lr][cc] = *(const float4*)&Kb[gaddr];
            *(float4*)&Vt[lr][cc] = *(const float4*)&Vb[gaddr];
        }
        if (t < 32) {
            const float ang = 1.57079632679489662f * (float)(lbase + t + 1) / (float)L_DIM;
            sT[t] = sinf(ang);
            cT[t] = cosf(ang);
        }
        __syncthreads();
#pragma unroll 4
        for (int lr = 0; lr < 32; ++lr) {
            const float sl = sT[lr], cl = cT[lr];
            const float k0v = Kt[lr][i0], k1v = Kt[lr][i0 + 1];
            const float ks0 = k0v * sl, ks1 = k1v * sl;
            const float kc0 = k0v * cl, kc1 = k1v * cl;
            sk[0] += ks0; sk[1] += ks1; ck[0] += kc0; ck[1] += kc1;
            float v8[8];
            *(float4*)&v8[0] = *(float4*)&Vt[lr][j0];
            *(float4*)&v8[4] = *(float4*)&Vt[lr][j0 + 4];
#pragma unroll
            for (int jj = 0; jj < 8; ++jj) {
                S[0][jj] = fmaf(ks0, v8[jj], S[0][jj]);
                S[1][jj] = fmaf(ks1, v8[jj], S[1][jj]);
                Cc[0][jj] = fmaf(kc0, v8[jj], Cc[0][jj]);
                Cc[1][jj] = fmaf(kc1, v8[jj], Cc[1][jj]);
            }
        }
        __syncthreads();
    }

    float* outp = kv + (size_t)g * TWO_D * D_DIM;
#pragma unroll
    for (int ii = 0; ii < 2; ++ii)
#pragma unroll
        for (int jj = 0; jj < 8; ++jj) {
            atomicAdd(&outp[(size_t)(i0 + ii) * D_DIM + j0 + jj], S[ii][jj]);
            atomicAdd(&outp[(size_t)(64 + i0 + ii) * D_DIM + j0 + jj], Cc[ii][jj]);
        }
    if (gj == 0) {
        float* ksb = ksum + (size_t)g * TWO_D;
        atomicAdd(&ksb[i0], sk[0]);
        atomicAdd(&ksb[i0 + 1], sk[1]);
        atomicAdd(&ksb[64 + i0], ck[0]);
        atomicAdd(&ksb[64 + i0 + 1], ck[1]);
    }
}

// ---------------------------------------------------------------------------
// attn: z + attn = z * q_ @ kv, emitted directly as bf16 hi/lo for final GEMM.
// ---------------------------------------------------------------------------
__global__ __launch_bounds__(256) void attn_kernel(const float* __restrict__ Q,
                                                   const float* __restrict__ kv,
                                                   const float* __restrict__ ksum,
                                                   ushort* __restrict__ attnHi,
                                                   ushort* __restrict__ attnLo) {
    const int g = blockIdx.x;
    const int lt = blockIdx.y;
    const int nb = g >> 4, hh = g & 15;
    const int t = threadIdx.x;

    __shared__ float kvs[TWO_D][64];
    __shared__ float qT[TWO_D][64];
    __shared__ float sTab[64], cTab[64], ksS[TWO_D], pz[64][4], zs[64];

    {
        const float4* kv4 = (const float4*)(kv + (size_t)g * TWO_D * D_DIM);
        float4* kvs4 = (float4*)&kvs[0][0];
        for (int s = t; s < TWO_D * D_DIM / 4; s += 256) kvs4[s] = kv4[s];
    }
    if (t < TWO_D) ksS[t] = ksum[(size_t)g * TWO_D + t];

    const int lbase = lt * 64;
    if (t < 64) {
        const float ang = 1.57079632679489662f * (float)(lbase + t + 1) / (float)L_DIM;
        sTab[t] = sinf(ang);
        cTab[t] = cosf(ang);
    }

    const int lq = t >> 2;
    const int dq = (t & 3) * 16;
    float qv[16];
    {
        const float* qrow = Q + (size_t)((lbase + lq) * N_DIM + nb) * E_DIM + hh * 64 + dq;
        *(float4*)&qv[0] = *(const float4*)&qrow[0];
        *(float4*)&qv[4] = *(const float4*)&qrow[4];
        *(float4*)&qv[8] = *(const float4*)&qrow[8];
        *(float4*)&qv[12] = *(const float4*)&qrow[12];
    }
    __syncthreads();

    {
        const float sl = sTab[lq], cl = cTab[lq];
#pragma unroll
        for (int jj = 0; jj < 16; ++jj) {
            qT[dq + jj][lq] = qv[jj] * sl;
            qT[64 + dq + jj][lq] = qv[jj] * cl;
        }
    }
    __syncthreads();

    {
        const int lz = t >> 2, qz = t & 3;
        float p = 0.f;
#pragma unroll
        for (int i = 0; i < 32; ++i) p = fmaf(qT[qz * 32 + i][lz], ksS[qz * 32 + i], p);
        pz[lz][qz] = p;
    }
    __syncthreads();
    if (t < 64) {
        const float s = pz[t][0] + pz[t][1] + pz[t][2] + pz[t][3];
        zs[t] = 1.0f / fmaxf(s, 1e-6f);
    }
    __syncthreads();

    const int ml = (t >> 4) * 4;
    const int nd = (t & 15) * 4;
    float acc[4][4];
#pragma unroll
    for (int i = 0; i < 4; ++i)
#pragma unroll
        for (int jj = 0; jj < 4; ++jj) acc[i][jj] = 0.f;

    for (int i = 0; i < TWO_D; ++i) {
        float4 a = *(float4*)&qT[i][ml];
        float4 b = *(float4*)&kvs[i][nd];
        acc[0][0] = fmaf(a.x, b.x, acc[0][0]); acc[0][1] = fmaf(a.x, b.y, acc[0][1]);
        acc[0][2] = fmaf(a.x, b.z, acc[0][2]); acc[0][3] = fmaf(a.x, b.w, acc[0][3]);
        acc[1][0] = fmaf(a.y, b.x, acc[1][0]); acc[1][1] = fmaf(a.y, b.y, acc[1][1]);
        acc[1][2] = fmaf(a.y, b.z, acc[1][2]); acc[1][3] = fmaf(a.y, b.w, acc[1][3]);
        acc[2][0] = fmaf(a.z, b.x, acc[2][0]); acc[2][1] = fmaf(a.z, b.y, acc[2][1]);
        acc[2][2] = fmaf(a.z, b.z, acc[2][2]); acc[2][3] = fmaf(a.z, b.w, acc[2][3]);
        acc[3][0] = fmaf(a.w, b.x, acc[3][0]); acc[3][1] = fmaf(a.w, b.y, acc[3][1]);
        acc[3][2] = fmaf(a.w, b.z, acc[3][2]); acc[3][3] = fmaf(a.w, b.w, acc[3][3]);
    }

#pragma unroll
    for (int r = 0; r < 4; ++r) {
        const float z = zs[ml + r];
        const float o0 = acc[r][0] * z, o1 = acc[r][1] * z;
        const float o2 = acc[r][2] * z, o3 = acc[r][3] * z;
        ushort4 hv, lv;
        hv.x = f2bf(o0); lv.x = f2bf(o0 - bf2f(hv.x));
        hv.y = f2bf(o1); lv.y = f2bf(o1 - bf2f(hv.y));
        hv.z = f2bf(o2); lv.z = f2bf(o2 - bf2f(hv.z));
        hv.w = f2bf(o3); lv.w = f2bf(o3 - bf2f(hv.w));
        const size_t base = (size_t)((lbase + ml + r) * N_DIM + nb) * E_DIM + hh * 64 + nd;
        *(ushort4*)&attnHi[base] = hv;
        *(ushort4*)&attnLo[base] = lv;
    }
}

// ---------------------------------------------------------------------------
extern "C" void kernel_launch(void* const* d_in, const int* in_sizes, int n_in,
                              void* d_out, int out_size, void* d_ws, size_t ws_size,
                              hipStream_t stream) {
    const float* X = (const float*)d_in[0];
    const float* Wq = (const float*)d_in[1];
    const float* Wk = (const float*)d_in[2];
    const float* Wv = (const float*)d_in[3];
    const float* Wo = (const float*)d_in[4];
    float* out = (float*)d_out;

    char* ws = (char*)d_ws;
    ushort* Xhi = (ushort*)(ws + 0);            // 33.55 MB (later: attnHi)
    ushort* Xlo = (ushort*)(ws + 33554432);     // 33.55 MB (later: attnLo)
    ushort* Whi = (ushort*)(ws + 67108864);     // 4 x 2 MB (q,k,v,o)
    ushort* Wlo = (ushort*)(ws + 75497472);     // 4 x 2 MB
    float* kv   = (float*)(ws + 83886080);      // 4.19 MB
    float* ksum = (float*)(ws + 88080384);      // 64 KB
    float* bufA = (float*)(ws + 88145920);      // 64 MB (V, then Q)
    // total ~148 MB

    const size_t WMAT = (size_t)E_DIM * E_DIM;  // 1048576

    hipMemsetAsync(kv, 0, (size_t)NHEADS * TWO_D * D_DIM * 4 + (size_t)NHEADS * TWO_D * 4, stream);

    split_fp32<<<2048, 256, 0, stream>>>(X, Xhi, Xlo, M_DIM * E_DIM / 4);
    split_fp32<<<256, 256, 0, stream>>>(Wq, Whi + 0 * WMAT, Wlo + 0 * WMAT, E_DIM * E_DIM / 4);
    split_fp32<<<256, 256, 0, stream>>>(Wk, Whi + 1 * WMAT, Wlo + 1 * WMAT, E_DIM * E_DIM / 4);
    split_fp32<<<256, 256, 0, stream>>>(Wv, Whi + 2 * WMAT, Wlo + 2 * WMAT, E_DIM * E_DIM / 4);
    split_fp32<<<256, 256, 0, stream>>>(Wo, Whi + 3 * WMAT, Wlo + 3 * WMAT, E_DIM * E_DIM / 4);

    // K = relu(X Wk^T) -> d_out (scratch until final GEMM)
    gemm_split<1><<<1024, 256, 0, stream>>>(Xhi, Xlo, Whi + 1 * WMAT, Wlo + 1 * WMAT, out);
    // V = X Wv^T -> bufA
    gemm_split<0><<<1024, 256, 0, stream>>>(Xhi, Xlo, Whi + 2 * WMAT, Wlo + 2 * WMAT, bufA);
    // kv / ksum (atomic accumulate)
    kv_partial<<<dim3(NHEADS, CH), 256, 0, stream>>>(out, bufA, kv, ksum);
    // Q = relu(X Wq^T) -> bufA (V dead)
    gemm_split<1><<<1024, 256, 0, stream>>>(Xhi, Xlo, Whi + 0 * WMAT, Wlo + 0 * WMAT, bufA);
    // attn -> bf16 hi/lo into X-split region (X dead)
    attn_kernel<<<dim3(NHEADS, L_DIM / 64), 256, 0, stream>>>(bufA, kv, ksum, Xhi, Xlo);
    // out = attn Wo^T
    gemm_split<0><<<1024, 256, 0, stream>>>(Xhi, Xlo, Whi + 3 * WMAT, Wlo + 3 * WMAT, out);
}

// Round 3
// 602.617 us; speedup vs baseline: 2.9372x; 1.2336x over previous
//
#include <hip/hip_runtime.h>
#include <math.h>

#define L_DIM 2048
#define N_DIM 8
#define E_DIM 1024
#define H_DIM 16
#define D_DIM 64
#define M_DIM (L_DIM * N_DIM)     // 16384
#define NHEADS (N_DIM * H_DIM)    // 128
#define TWO_D 128
#define K_DIM 1024
#define CH 4                      // L-chunks for kv partials
#define LCH (L_DIM / CH)          // 512

// per-chunk kv partial stride (floats): 128 heads * 128*64 kv + 128*128 ksum
#define KV_ELEMS (NHEADS * TWO_D * D_DIM)   // 1048576
#define KS_ELEMS (NHEADS * TWO_D)           // 16384
#define CSTRIDE (KV_ELEMS + KS_ELEMS)       // 1064960 floats

typedef __attribute__((ext_vector_type(8))) __bf16 bf16x8;
typedef __attribute__((ext_vector_type(4))) float f32x4;

__device__ __forceinline__ ushort f2bf(float x) {
    union { float f; unsigned u; } a; a.f = x;
    unsigned r = a.u + 0x7fffu + ((a.u >> 16) & 1u);
    return (ushort)(r >> 16);
}
__device__ __forceinline__ float bf2f(ushort h) {
    union { unsigned u; float f; } a; a.u = ((unsigned)h) << 16;
    return a.f;
}

__device__ __forceinline__ void gload_lds16(const void* g, void* l) {
    __builtin_amdgcn_global_load_lds((const __attribute__((address_space(1))) void*)g,
                                     (__attribute__((address_space(3))) void*)l, 16, 0, 0);
}

// ---------------------------------------------------------------------------
// split fp32 -> bf16 hi + bf16 lo
// ---------------------------------------------------------------------------
__global__ __launch_bounds__(256) void split_fp32(const float* __restrict__ in,
                                                  ushort* __restrict__ hi,
                                                  ushort* __restrict__ lo, int n4) {
    int i = blockIdx.x * 256 + threadIdx.x;
    const int stride = gridDim.x * 256;
    for (; i < n4; i += stride) {
        float4 v = ((const float4*)in)[i];
        ushort h0 = f2bf(v.x), h1 = f2bf(v.y), h2 = f2bf(v.z), h3 = f2bf(v.w);
        ushort l0 = f2bf(v.x - bf2f(h0)), l1 = f2bf(v.y - bf2f(h1));
        ushort l2 = f2bf(v.z - bf2f(h2)), l3 = f2bf(v.w - bf2f(h3));
        ((ushort4*)hi)[i] = make_ushort4(h0, h1, h2, h3);
        ((ushort4*)lo)[i] = make_ushort4(l0, l1, l2, l3);
    }
}

// ---------------------------------------------------------------------------
// split-bf16 MFMA GEMM-NT, 128x128 tile, BK=32, 4 waves.
// OUTMODE 0: C[m][gc] row-major fp32, no relu       (final projection)
// OUTMODE 1: head-major fp32 + relu                 (Q)
// OUTMODE 2: fused K|V -> head-major; K relu, V not (C = K base, C2 = V base)
// head-major: m=(l*8+nb8), gc=(hh*64+d) -> [(nb8*16+hh)*2048 + l]*64 + d
// ---------------------------------------------------------------------------
__device__ __forceinline__ void compute_step(const ushort (*buf)[128 * 32],
                                             const int* aoff, const int* boff,
                                             f32x4 acc[4][4]) {
    bf16x8 ah[4], al[4], bh[4], bl[4];
#pragma unroll
    for (int m = 0; m < 4; ++m) {
        ah[m] = *(const bf16x8*)&buf[0][aoff[m]];
        al[m] = *(const bf16x8*)&buf[1][aoff[m]];
    }
#pragma unroll
    for (int n = 0; n < 4; ++n) {
        bh[n] = *(const bf16x8*)&buf[2][boff[n]];
        bl[n] = *(const bf16x8*)&buf[3][boff[n]];
    }
#pragma unroll
    for (int m = 0; m < 4; ++m)
#pragma unroll
        for (int n = 0; n < 4; ++n) {
            acc[m][n] = __builtin_amdgcn_mfma_f32_16x16x32_bf16(ah[m], bh[n], acc[m][n], 0, 0, 0);
            acc[m][n] = __builtin_amdgcn_mfma_f32_16x16x32_bf16(ah[m], bl[n], acc[m][n], 0, 0, 0);
            acc[m][n] = __builtin_amdgcn_mfma_f32_16x16x32_bf16(al[m], bh[n], acc[m][n], 0, 0, 0);
        }
}

template <int OUTMODE, int NBS>
__global__ __launch_bounds__(256) void gemm_split(const ushort* __restrict__ Ahi,
                                                  const ushort* __restrict__ Alo,
                                                  const ushort* __restrict__ Bhi,
                                                  const ushort* __restrict__ Blo,
                                                  float* __restrict__ C,
                                                  float* __restrict__ C2) {
    __shared__ ushort smem[2][4][128 * 32];  // 64 KiB

    const int t = threadIdx.x;
    const int wid = t >> 6;
    const int lane = t & 63;

    const int x = blockIdx.x;
    const int cxcd = x & 7;
    const int j = x >> 3;
    const int mb = cxcd * 16 + j / NBS;
    const int nb = j % NBS;
    const int m0 = mb * 128, n0 = nb * 128;

    const int srow = t >> 2;
    const int sch = t & 3;
    const int gch = sch ^ ((srow >> 1) & 3);
    const ushort* gA0 = Ahi + (size_t)(m0 + srow) * K_DIM + gch * 8;
    const ushort* gL0 = Alo + (size_t)(m0 + srow) * K_DIM + gch * 8;
    const ushort* gB0 = Bhi + (size_t)(n0 + srow) * K_DIM + gch * 8;
    const ushort* gC0 = Blo + (size_t)(n0 + srow) * K_DIM + gch * 8;
    const size_t half = (size_t)64 * K_DIM;

#define STAGE(b, koff)                                                        \
    do {                                                                      \
        gload_lds16(gA0 + (koff), &smem[b][0][wid * 512]);                    \
        gload_lds16(gA0 + half + (koff), &smem[b][0][2048 + wid * 512]);      \
        gload_lds16(gL0 + (koff), &smem[b][1][wid * 512]);                    \
        gload_lds16(gL0 + half + (koff), &smem[b][1][2048 + wid * 512]);      \
        gload_lds16(gB0 + (koff), &smem[b][2][wid * 512]);                    \
        gload_lds16(gB0 + half + (koff), &smem[b][2][2048 + wid * 512]);      \
        gload_lds16(gC0 + (koff), &smem[b][3][wid * 512]);                    \
        gload_lds16(gC0 + half + (koff), &smem[b][3][2048 + wid * 512]);      \
    } while (0)

    const int wm = wid >> 1, wn = wid & 1;
    const int lr = lane & 15;
    const int kc = lane >> 4;
    int aoff[4], boff[4];
#pragma unroll
    for (int m = 0; m < 4; ++m) {
        const int r = wm * 64 + m * 16 + lr;
        aoff[m] = r * 32 + ((kc ^ ((r >> 1) & 3)) << 3);
    }
#pragma unroll
    for (int n = 0; n < 4; ++n) {
        const int r = wn * 64 + n * 16 + lr;
        boff[n] = r * 32 + ((kc ^ ((r >> 1) & 3)) << 3);
    }

    f32x4 acc[4][4];
    const f32x4 zv = {0.f, 0.f, 0.f, 0.f};
#pragma unroll
    for (int m = 0; m < 4; ++m)
#pragma unroll
        for (int n = 0; n < 4; ++n) acc[m][n] = zv;

    STAGE(0, 0);
    __syncthreads();
#pragma unroll 1
    for (int kt = 0; kt < 31; ++kt) {
        const int b = kt & 1;
        STAGE(b ^ 1, (size_t)(kt + 1) * 32);
        compute_step(smem[b], aoff, boff, acc);
        __syncthreads();
    }
    compute_step(smem[1], aoff, boff, acc);

    const int erow = (lane >> 4) * 4;
    const int ecol = lane & 15;
#pragma unroll
    for (int m = 0; m < 4; ++m) {
        const int grb = m0 + wm * 64 + m * 16 + erow;
#pragma unroll
        for (int n = 0; n < 4; ++n) {
            const int gc = n0 + wn * 64 + n * 16 + ecol;
            f32x4 v = acc[m][n];
#pragma unroll
            for (int q = 0; q < 4; ++q) {
                const int gr = grb + q;
                float val = v[q];
                if constexpr (OUTMODE == 0) {
                    C[(size_t)gr * E_DIM + gc] = val;
                } else if constexpr (OUTMODE == 1) {
                    val = fmaxf(val, 0.f);
                    const int hh = gc >> 6, d = gc & 63;
                    C[((size_t)((gr & 7) * 16 + hh) * L_DIM + (gr >> 3)) * D_DIM + d] = val;
                } else {
                    const int mat = gc >> 10;          // 0 = K (relu), 1 = V
                    const int col = gc & 1023;
                    if (mat == 0) val = fmaxf(val, 0.f);
                    const int hh = col >> 6, d = col & 63;
                    float* dst = mat ? C2 : C;
                    dst[((size_t)((gr & 7) * 16 + hh) * L_DIM + (gr >> 3)) * D_DIM + d] = val;
                }
            }
        }
    }
#undef STAGE
}

// ---------------------------------------------------------------------------
// kv partials from head-major K/V: block (g, c) streams contiguous slices.
// Writes plain partials to kvp chunk c (no atomics).
// ---------------------------------------------------------------------------
__global__ __launch_bounds__(256) void kv_partial(const float* __restrict__ Kh,
                                                  const float* __restrict__ Vh,
                                                  float* __restrict__ kvp) {
    const int g = blockIdx.x;  // head 0..127
    const int c = blockIdx.y;  // chunk 0..CH-1
    const int t = threadIdx.x;

    __shared__ float Kt[32][64];
    __shared__ float Vt[32][64];
    __shared__ float sT[32], cT[32];

    const int gi = t >> 3;
    const int gj = t & 7;
    const int i0 = gi * 2, j0 = gj * 8;

    float S[2][8], Cc[2][8];
#pragma unroll
    for (int i = 0; i < 2; ++i)
#pragma unroll
        for (int jj = 0; jj < 8; ++jj) { S[i][jj] = 0.f; Cc[i][jj] = 0.f; }
    float sk[2] = {0.f, 0.f}, ck[2] = {0.f, 0.f};

    for (int lt = 0; lt < LCH; lt += 32) {
        const int lbase = c * LCH + lt;
        const float4* ks = (const float4*)&Kh[((size_t)g * L_DIM + lbase) * D_DIM];
        const float4* vs = (const float4*)&Vh[((size_t)g * L_DIM + lbase) * D_DIM];
        ((float4*)&Kt[0][0])[t] = ks[t];
        ((float4*)&Kt[0][0])[t + 256] = ks[t + 256];
        ((float4*)&Vt[0][0])[t] = vs[t];
        ((float4*)&Vt[0][0])[t + 256] = vs[t + 256];
        if (t < 32) {
            const float ang = 1.57079632679489662f * (float)(lbase + t + 1) / (float)L_DIM;
            sT[t] = sinf(ang);
            cT[t] = cosf(ang);
        }
        __syncthreads();
#pragma unroll 4
        for (int lr = 0; lr < 32; ++lr) {
            const float sl = sT[lr], cl = cT[lr];
            const float k0v = Kt[lr][i0], k1v = Kt[lr][i0 + 1];
            const float ks0 = k0v * sl, ks1 = k1v * sl;
            const float kc0 = k0v * cl, kc1 = k1v * cl;
            sk[0] += ks0; sk[1] += ks1; ck[0] += kc0; ck[1] += kc1;
            float v8[8];
            *(float4*)&v8[0] = *(float4*)&Vt[lr][j0];
            *(float4*)&v8[4] = *(float4*)&Vt[lr][j0 + 4];
#pragma unroll
            for (int jj = 0; jj < 8; ++jj) {
                S[0][jj] = fmaf(ks0, v8[jj], S[0][jj]);
                S[1][jj] = fmaf(ks1, v8[jj], S[1][jj]);
                Cc[0][jj] = fmaf(kc0, v8[jj], Cc[0][jj]);
                Cc[1][jj] = fmaf(kc1, v8[jj], Cc[1][jj]);
            }
        }
        __syncthreads();
    }

    float* kvb = kvp + (size_t)c * CSTRIDE + (size_t)g * TWO_D * D_DIM;
#pragma unroll
    for (int ii = 0; ii < 2; ++ii) {
        *(float4*)&kvb[(size_t)(i0 + ii) * D_DIM + j0] =
            make_float4(S[ii][0], S[ii][1], S[ii][2], S[ii][3]);
        *(float4*)&kvb[(size_t)(i0 + ii) * D_DIM + j0 + 4] =
            make_float4(S[ii][4], S[ii][5], S[ii][6], S[ii][7]);
        *(float4*)&kvb[(size_t)(64 + i0 + ii) * D_DIM + j0] =
            make_float4(Cc[ii][0], Cc[ii][1], Cc[ii][2], Cc[ii][3]);
        *(float4*)&kvb[(size_t)(64 + i0 + ii) * D_DIM + j0 + 4] =
            make_float4(Cc[ii][4], Cc[ii][5], Cc[ii][6], Cc[ii][7]);
    }
    if (gj == 0) {
        float* ksb = kvp + (size_t)c * CSTRIDE + KV_ELEMS + (size_t)g * TWO_D;
        ksb[i0] = sk[0];
        ksb[i0 + 1] = sk[1];
        ksb[64 + i0] = ck[0];
        ksb[64 + i0 + 1] = ck[1];
    }
}

// in-place reduce: kvp[0][i] = sum_c kvp[c][i]
__global__ __launch_bounds__(256) void reduce_kv(float* __restrict__ kvp) {
    const int idx = blockIdx.x * 256 + threadIdx.x;
    if (idx < CSTRIDE) {
        float s = kvp[idx];
#pragma unroll
        for (int c = 1; c < CH; ++c) s += kvp[(size_t)c * CSTRIDE + idx];
        kvp[idx] = s;
    }
}

// ---------------------------------------------------------------------------
// attn: head-major Q in, bf16 hi/lo (L,N,E) out.
// ---------------------------------------------------------------------------
__global__ __launch_bounds__(256) void attn_kernel(const float* __restrict__ Qh,
                                                   const float* __restrict__ kvp,
                                                   ushort* __restrict__ attnHi,
                                                   ushort* __restrict__ attnLo) {
    const int g = blockIdx.x;
    const int lt = blockIdx.y;
    const int nb = g >> 4, hh = g & 15;
    const int t = threadIdx.x;

    __shared__ float kvs[TWO_D][64];
    __shared__ float qT[TWO_D][64];
    __shared__ float sTab[64], cTab[64], ksS[TWO_D], pz[64][4], zs[64];

    {
        const float4* kv4 = (const float4*)(kvp + (size_t)g * TWO_D * D_DIM);
        float4* kvs4 = (float4*)&kvs[0][0];
        for (int s = t; s < TWO_D * D_DIM / 4; s += 256) kvs4[s] = kv4[s];
    }
    if (t < TWO_D) ksS[t] = kvp[KV_ELEMS + (size_t)g * TWO_D + t];

    const int lbase = lt * 64;
    if (t < 64) {
        const float ang = 1.57079632679489662f * (float)(lbase + t + 1) / (float)L_DIM;
        sTab[t] = sinf(ang);
        cTab[t] = cosf(ang);
    }

    const int lq = t >> 2;
    const int dq = (t & 3) * 16;
    float qv[16];
    {
        const float* qrow = Qh + ((size_t)g * L_DIM + lbase + lq) * D_DIM + dq;
        *(float4*)&qv[0] = *(const float4*)&qrow[0];
        *(float4*)&qv[4] = *(const float4*)&qrow[4];
        *(float4*)&qv[8] = *(const float4*)&qrow[8];
        *(float4*)&qv[12] = *(const float4*)&qrow[12];
    }
    __syncthreads();

    {
        const float sl = sTab[lq], cl = cTab[lq];
#pragma unroll
        for (int jj = 0; jj < 16; ++jj) {
            qT[dq + jj][lq] = qv[jj] * sl;
            qT[64 + dq + jj][lq] = qv[jj] * cl;
        }
    }
    __syncthreads();

    {
        const int lz = t >> 2, qz = t & 3;
        float p = 0.f;
#pragma unroll
        for (int i = 0; i < 32; ++i) p = fmaf(qT[qz * 32 + i][lz], ksS[qz * 32 + i], p);
        pz[lz][qz] = p;
    }
    __syncthreads();
    if (t < 64) {
        const float s = pz[t][0] + pz[t][1] + pz[t][2] + pz[t][3];
        zs[t] = 1.0f / fmaxf(s, 1e-6f);
    }
    __syncthreads();

    const int ml = (t >> 4) * 4;
    const int nd = (t & 15) * 4;
    float acc[4][4];
#pragma unroll
    for (int i = 0; i < 4; ++i)
#pragma unroll
        for (int jj = 0; jj < 4; ++jj) acc[i][jj] = 0.f;

    for (int i = 0; i < TWO_D; ++i) {
        float4 a = *(float4*)&qT[i][ml];
        float4 b = *(float4*)&kvs[i][nd];
        acc[0][0] = fmaf(a.x, b.x, acc[0][0]); acc[0][1] = fmaf(a.x, b.y, acc[0][1]);
        acc[0][2] = fmaf(a.x, b.z, acc[0][2]); acc[0][3] = fmaf(a.x, b.w, acc[0][3]);
        acc[1][0] = fmaf(a.y, b.x, acc[1][0]); acc[1][1] = fmaf(a.y, b.y, acc[1][1]);
        acc[1][2] = fmaf(a.y, b.z, acc[1][2]); acc[1][3] = fmaf(a.y, b.w, acc[1][3]);
        acc[2][0] = fmaf(a.z, b.x, acc[2][0]); acc[2][1] = fmaf(a.z, b.y, acc[2][1]);
        acc[2][2] = fmaf(a.z, b.z, acc[2][2]); acc[2][3] = fmaf(a.z, b.w, acc[2][3]);
        acc[3][0] = fmaf(a.w, b.x, acc[3][0]); acc[3][1] = fmaf(a.w, b.y, acc[3][1]);
        acc[3][2] = fmaf(a.w, b.z, acc[3][2]); acc[3][3] = fmaf(a.w, b.w, acc[3][3]);
    }

#pragma unroll
    for (int r = 0; r < 4; ++r) {
        const float z = zs[ml + r];
        const float o0 = acc[r][0] * z, o1 = acc[r][1] * z;
        const float o2 = acc[r][2] * z, o3 = acc[r][3] * z;
        ushort4 hv, lv;
        hv.x = f2bf(o0); lv.x = f2bf(o0 - bf2f(hv.x));
        hv.y = f2bf(o1); lv.y = f2bf(o1 - bf2f(hv.y));
        hv.z = f2bf(o2); lv.z = f2bf(o2 - bf2f(hv.z));
        hv.w = f2bf(o3); lv.w = f2bf(o3 - bf2f(hv.w));
        const size_t base = (size_t)((lbase + ml + r) * N_DIM + nb) * E_DIM + hh * 64 + nd;
        *(ushort4*)&attnHi[base] = hv;
        *(ushort4*)&attnLo[base] = lv;
    }
}

// ---------------------------------------------------------------------------
extern "C" void kernel_launch(void* const* d_in, const int* in_sizes, int n_in,
                              void* d_out, int out_size, void* d_ws, size_t ws_size,
                              hipStream_t stream) {
    const float* X = (const float*)d_in[0];
    const float* Wq = (const float*)d_in[1];
    const float* Wk = (const float*)d_in[2];
    const float* Wv = (const float*)d_in[3];
    const float* Wo = (const float*)d_in[4];
    float* out = (float*)d_out;

    char* ws = (char*)d_ws;
    ushort* Xhi = (ushort*)(ws + 0);            // 32 MiB (later attnHi)
    ushort* Xlo = (ushort*)(ws + 33554432);     // 32 MiB (later attnLo)
    ushort* Whi = (ushort*)(ws + 67108864);     // 4 x 2 MiB (q,k,v,o)
    ushort* Wlo = (ushort*)(ws + 75497472);     // 4 x 2 MiB
    float* kvp  = (float*)(ws + 83886080);      // CH x 4.06 MiB = 16.25 MiB
    float* bufA = (float*)(ws + 100925440);     // 64 MiB (Vh)
    // peak = 160.25 MiB (< 164.6 MiB proven in round 1)

    float* Kh = out;   // d_out as scratch: Kh, then Qh, then final output
    float* Vh = bufA;
    float* Qh = out;

    const size_t WMAT = (size_t)E_DIM * E_DIM;

    split_fp32<<<2048, 256, 0, stream>>>(X, Xhi, Xlo, M_DIM * E_DIM / 4);
    split_fp32<<<256, 256, 0, stream>>>(Wq, Whi + 0 * WMAT, Wlo + 0 * WMAT, E_DIM * E_DIM / 4);
    split_fp32<<<256, 256, 0, stream>>>(Wk, Whi + 1 * WMAT, Wlo + 1 * WMAT, E_DIM * E_DIM / 4);
    split_fp32<<<256, 256, 0, stream>>>(Wv, Whi + 2 * WMAT, Wlo + 2 * WMAT, E_DIM * E_DIM / 4);
    split_fp32<<<256, 256, 0, stream>>>(Wo, Whi + 3 * WMAT, Wlo + 3 * WMAT, E_DIM * E_DIM / 4);

    // fused K|V projection: B = [Wk; Wv] (2048 rows), K->Kh(relu), V->Vh
    gemm_split<2, 16><<<2048, 256, 0, stream>>>(Xhi, Xlo, Whi + 1 * WMAT, Wlo + 1 * WMAT, Kh, Vh);

    // kv partials + reduce (no atomics)
    kv_partial<<<dim3(NHEADS, CH), 256, 0, stream>>>(Kh, Vh, kvp);
    reduce_kv<<<(CSTRIDE + 255) / 256, 256, 0, stream>>>(kvp);

    // Q projection (Kh dead -> reuse d_out)
    gemm_split<1, 8><<<1024, 256, 0, stream>>>(Xhi, Xlo, Whi + 0 * WMAT, Wlo + 0 * WMAT, Qh, nullptr);

    // attn -> bf16 hi/lo into X region (X dead after Q GEMM)
    attn_kernel<<<dim3(NHEADS, L_DIM / 64), 256, 0, stream>>>(Qh, kvp, Xhi, Xlo);

    // out = attn Wo^T (Qh dead)
    gemm_split<0, 8><<<1024, 256, 0, stream>>>(Xhi, Xlo, Whi + 3 * WMAT, Wlo + 3 * WMAT, out, nullptr);
}

// Round 5
// 574.633 us; speedup vs baseline: 3.0802x; 1.0487x over previous
//
#include <hip/hip_runtime.h>
#include <math.h>

#define L_DIM 2048
#define N_DIM 8
#define E_DIM 1024
#define H_DIM 16
#define D_DIM 64
#define M_DIM (L_DIM * N_DIM)     // 16384
#define NHEADS (N_DIM * H_DIM)    // 128
#define TWO_D 128
#define K_DIM 1024
#define CH 4                      // L-chunks for kv partials
#define LCH (L_DIM / CH)          // 512

#define KV_ELEMS (NHEADS * TWO_D * D_DIM)   // 1048576
#define KS_ELEMS (NHEADS * TWO_D)           // 16384
#define CSTRIDE (KV_ELEMS + KS_ELEMS)       // 1064960 floats per chunk

typedef __attribute__((ext_vector_type(8))) __bf16 bf16x8;
typedef __attribute__((ext_vector_type(4))) float f32x4;

__device__ __forceinline__ ushort f2bf(float x) {
    union { float f; unsigned u; } a; a.f = x;
    unsigned r = a.u + 0x7fffu + ((a.u >> 16) & 1u);
    return (ushort)(r >> 16);
}
__device__ __forceinline__ float bf2f(ushort h) {
    union { unsigned u; float f; } a; a.u = ((unsigned)h) << 16;
    return a.f;
}

__device__ __forceinline__ void gload_lds16(const void* g, void* l) {
    __builtin_amdgcn_global_load_lds((const __attribute__((address_space(1))) void*)g,
                                     (__attribute__((address_space(3))) void*)l, 16, 0, 0);
}

// ---------------------------------------------------------------------------
// split fp32 -> bf16 hi + lo
// ---------------------------------------------------------------------------
__global__ __launch_bounds__(256) void split_fp32(const float* __restrict__ in,
                                                  ushort* __restrict__ hi,
                                                  ushort* __restrict__ lo, int n4) {
    int i = blockIdx.x * 256 + threadIdx.x;
    const int stride = gridDim.x * 256;
    for (; i < n4; i += stride) {
        float4 v = ((const float4*)in)[i];
        ushort h0 = f2bf(v.x), h1 = f2bf(v.y), h2 = f2bf(v.z), h3 = f2bf(v.w);
        ushort l0 = f2bf(v.x - bf2f(h0)), l1 = f2bf(v.y - bf2f(h1));
        ushort l2 = f2bf(v.z - bf2f(h2)), l3 = f2bf(v.w - bf2f(h3));
        ((ushort4*)hi)[i] = make_ushort4(h0, h1, h2, h3);
        ((ushort4*)lo)[i] = make_ushort4(l0, l1, l2, l3);
    }
}

// all four weight matrices in one launch; blockIdx.y selects the matrix
__global__ __launch_bounds__(256) void split_w4(const float* __restrict__ w0,
                                                const float* __restrict__ w1,
                                                const float* __restrict__ w2,
                                                const float* __restrict__ w3,
                                                ushort* __restrict__ hi,
                                                ushort* __restrict__ lo) {
    const int midx = blockIdx.y;
    const float* src = (midx == 0) ? w0 : (midx == 1) ? w1 : (midx == 2) ? w2 : w3;
    hi += (size_t)midx * E_DIM * E_DIM;
    lo += (size_t)midx * E_DIM * E_DIM;
    const int n4 = E_DIM * E_DIM / 4;
    int i = blockIdx.x * 256 + threadIdx.x;
    const int stride = gridDim.x * 256;
    for (; i < n4; i += stride) {
        float4 v = ((const float4*)src)[i];
        ushort h0 = f2bf(v.x), h1 = f2bf(v.y), h2 = f2bf(v.z), h3 = f2bf(v.w);
        ushort l0 = f2bf(v.x - bf2f(h0)), l1 = f2bf(v.y - bf2f(h1));
        ushort l2 = f2bf(v.z - bf2f(h2)), l3 = f2bf(v.w - bf2f(h3));
        ((ushort4*)hi)[i] = make_ushort4(h0, h1, h2, h3);
        ((ushort4*)lo)[i] = make_ushort4(l0, l1, l2, l3);
    }
}

// ---------------------------------------------------------------------------
// split-bf16 MFMA GEMM-NT, 128(M) x 256(N) tile, BK=32, 8 waves (512 thr).
// 3-buffer LDS rotation, counted vmcnt(6) boundaries (T4), setprio (T5),
// XOR-swizzled LDS (T2), XCD-grouped blocks (T1).
// Grid MUST be 128 * NBS blocks (128 M-tiles x NBS N-tiles).
// OUTMODE 0: row-major fp32                      (final projection)
// OUTMODE 1: head-major fp32 + relu              (Q)
// OUTMODE 2: fused K|V head-major; K relu only   (C=K, C2=V)
// ---------------------------------------------------------------------------
template <int OUTMODE, int NBS>
__global__ __launch_bounds__(512) void gemm3(const ushort* __restrict__ Ahi,
                                             const ushort* __restrict__ Alo,
                                             const ushort* __restrict__ Bhi,
                                             const ushort* __restrict__ Blo,
                                             float* __restrict__ C,
                                             float* __restrict__ C2) {
    // buffer layout (ushorts): Ah[0,4096) Al[4096,8192) Bh[8192,16384) Bl[16384,24576)
    __shared__ ushort smem[3][24576];  // 144 KiB

    const int t = threadIdx.x;
    const int wid = t >> 6;
    const int lane = t & 63;

    // T1: XCD-grouped decomposition. grid = 128*NBS, 16*NBS blocks per XCD.
    const int x = blockIdx.x;
    const int cxcd = x & 7;
    const int j = x >> 3;                     // 0 .. 16*NBS-1
    const int mb = cxcd * 16 + j / NBS;       // 0..127
    const int nb = j % NBS;
    const int m0 = mb * 128, n0 = nb * 256;

    // ---- staging source addresses (inverse-swizzled; LDS dest linear) ----
    const int srow = t >> 2;                  // 0..127
    const int sch = t & 3;
    const int gch = sch ^ ((srow >> 1) & 3);  // swizzle invariant under row+128
    const ushort* sAh = Ahi + (size_t)(m0 + srow) * K_DIM + gch * 8;
    const ushort* sAl = Alo + (size_t)(m0 + srow) * K_DIM + gch * 8;
    const ushort* sBh = Bhi + (size_t)(n0 + srow) * K_DIM + gch * 8;
    const ushort* sBl = Blo + (size_t)(n0 + srow) * K_DIM + gch * 8;
    const size_t B2 = (size_t)128 * K_DIM;

#define STAGE3(b, kt2)                                                   \
    do {                                                                 \
        const size_t kc_ = (size_t)(kt2) * 32;                           \
        gload_lds16(sAh + kc_, &smem[b][0] + wid * 512);                 \
        gload_lds16(sAl + kc_, &smem[b][4096] + wid * 512);              \
        gload_lds16(sBh + kc_, &smem[b][8192] + wid * 512);              \
        gload_lds16(sBh + B2 + kc_, &smem[b][12288] + wid * 512);        \
        gload_lds16(sBl + kc_, &smem[b][16384] + wid * 512);             \
        gload_lds16(sBl + B2 + kc_, &smem[b][20480] + wid * 512);        \
    } while (0)

    // ---- fragment read offsets (swizzled) ----
    const int wm = wid >> 2;       // 0..1 -> M half
    const int wn = wid & 3;        // 0..3 -> N quarter
    const int lr = lane & 15;
    const int kc = lane >> 4;
    int aoff[4], boff[4];
#pragma unroll
    for (int m = 0; m < 4; ++m) {
        const int r = wm * 64 + m * 16 + lr;
        aoff[m] = r * 32 + ((kc ^ ((r >> 1) & 3)) << 3);
    }
#pragma unroll
    for (int n = 0; n < 4; ++n) {
        const int r = wn * 64 + n * 16 + lr;
        boff[n] = r * 32 + ((kc ^ ((r >> 1) & 3)) << 3);
    }

    f32x4 acc[4][4];
    const f32x4 zv = {0.f, 0.f, 0.f, 0.f};
#pragma unroll
    for (int m = 0; m < 4; ++m)
#pragma unroll
        for (int n = 0; n < 4; ++n) acc[m][n] = zv;

    const int NK = K_DIM / 32;  // 32

    // prologue: prefetch kt=0,1
    STAGE3(0, 0);
    STAGE3(1, 1);
    asm volatile("s_waitcnt vmcnt(6)" ::: "memory");  // kt0 landed
    __builtin_amdgcn_s_barrier();
    asm volatile("" ::: "memory");

#pragma unroll 1
    for (int kt = 0; kt < NK; ++kt) {
        const int cur = kt % 3;
        if (kt + 2 < NK) STAGE3((kt + 2) % 3, kt + 2);

        const ushort* bb = smem[cur];
        bf16x8 bh[4], bl[4];
#pragma unroll
        for (int n = 0; n < 4; ++n) {
            bh[n] = *(const bf16x8*)&bb[8192 + boff[n]];
            bl[n] = *(const bf16x8*)&bb[16384 + boff[n]];
        }
#pragma unroll
        for (int m = 0; m < 4; ++m) {
            const bf16x8 ah = *(const bf16x8*)&bb[aoff[m]];
            const bf16x8 al = *(const bf16x8*)&bb[4096 + aoff[m]];
            __builtin_amdgcn_s_setprio(1);
#pragma unroll
            for (int n = 0; n < 4; ++n) {
                acc[m][n] = __builtin_amdgcn_mfma_f32_16x16x32_bf16(ah, bh[n], acc[m][n], 0, 0, 0);
                acc[m][n] = __builtin_amdgcn_mfma_f32_16x16x32_bf16(ah, bl[n], acc[m][n], 0, 0, 0);
                acc[m][n] = __builtin_amdgcn_mfma_f32_16x16x32_bf16(al, bh[n], acc[m][n], 0, 0, 0);
            }
            __builtin_amdgcn_s_setprio(0);
        }

        if (kt < NK - 1) {
            // boundary: kt+1's loads must be landed; kt+2's (6 newest) may fly
            if (kt + 2 < NK) {
                asm volatile("s_waitcnt vmcnt(6)" ::: "memory");
            } else {
                asm volatile("s_waitcnt vmcnt(0)" ::: "memory");
            }
            __builtin_amdgcn_s_barrier();
            asm volatile("" ::: "memory");
        }
    }

    // ---- epilogue: C/D layout col=lane&15, row=(lane>>4)*4+q ----
    const int erow = (lane >> 4) * 4;
    const int ecol = lane & 15;
#pragma unroll
    for (int m = 0; m < 4; ++m) {
        const int grb = m0 + wm * 64 + m * 16 + erow;
#pragma unroll
        for (int n = 0; n < 4; ++n) {
            const int gc = n0 + wn * 64 + n * 16 + ecol;
            f32x4 v = acc[m][n];
#pragma unroll
            for (int q = 0; q < 4; ++q) {
                const int gr = grb + q;
                float val = v[q];
                if constexpr (OUTMODE == 0) {
                    C[(size_t)gr * E_DIM + gc] = val;
                } else if constexpr (OUTMODE == 1) {
                    val = fmaxf(val, 0.f);
                    const int hh = gc >> 6, d = gc & 63;
                    C[((size_t)((gr & 7) * 16 + hh) * L_DIM + (gr >> 3)) * D_DIM + d] = val;
                } else {
                    const int mat = gc >> 10;  // 0 = K (relu), 1 = V
                    const int col = gc & 1023;
                    if (mat == 0) val = fmaxf(val, 0.f);
                    const int hh = col >> 6, d = col & 63;
                    float* dst = mat ? C2 : C;
                    dst[((size_t)((gr & 7) * 16 + hh) * L_DIM + (gr >> 3)) * D_DIM + d] = val;
                }
            }
        }
    }
#undef STAGE3
}

// ---------------------------------------------------------------------------
// kv partials from head-major K/V (contiguous streams, no atomics)
// ---------------------------------------------------------------------------
__global__ __launch_bounds__(256) void kv_partial(const float* __restrict__ Kh,
                                                  const float* __restrict__ Vh,
                                                  float* __restrict__ kvp) {
    const int g = blockIdx.x;
    const int c = blockIdx.y;
    const int t = threadIdx.x;

    __shared__ float Kt[32][64];
    __shared__ float Vt[32][64];
    __shared__ float sT[32], cT[32];

    const int gi = t >> 3;
    const int gj = t & 7;
    const int i0 = gi * 2, j0 = gj * 8;

    float S[2][8], Cc[2][8];
#pragma unroll
    for (int i = 0; i < 2; ++i)
#pragma unroll
        for (int jj = 0; jj < 8; ++jj) { S[i][jj] = 0.f; Cc[i][jj] = 0.f; }
    float sk[2] = {0.f, 0.f}, ck[2] = {0.f, 0.f};

    for (int lt = 0; lt < LCH; lt += 32) {
        const int lbase = c * LCH + lt;
        const float4* ks = (const float4*)&Kh[((size_t)g * L_DIM + lbase) * D_DIM];
        const float4* vs = (const float4*)&Vh[((size_t)g * L_DIM + lbase) * D_DIM];
        ((float4*)&Kt[0][0])[t] = ks[t];
        ((float4*)&Kt[0][0])[t + 256] = ks[t + 256];
        ((float4*)&Vt[0][0])[t] = vs[t];
        ((float4*)&Vt[0][0])[t + 256] = vs[t + 256];
        if (t < 32) {
            const float ang = 1.57079632679489662f * (float)(lbase + t + 1) / (float)L_DIM;
            sT[t] = sinf(ang);
            cT[t] = cosf(ang);
        }
        __syncthreads();
#pragma unroll 4
        for (int lr = 0; lr < 32; ++lr) {
            const float sl = sT[lr], cl = cT[lr];
            const float k0v = Kt[lr][i0], k1v = Kt[lr][i0 + 1];
            const float ks0 = k0v * sl, ks1 = k1v * sl;
            const float kc0 = k0v * cl, kc1 = k1v * cl;
            sk[0] += ks0; sk[1] += ks1; ck[0] += kc0; ck[1] += kc1;
            float v8[8];
            *(float4*)&v8[0] = *(float4*)&Vt[lr][j0];
            *(float4*)&v8[4] = *(float4*)&Vt[lr][j0 + 4];
#pragma unroll
            for (int jj = 0; jj < 8; ++jj) {
                S[0][jj] = fmaf(ks0, v8[jj], S[0][jj]);
                S[1][jj] = fmaf(ks1, v8[jj], S[1][jj]);
                Cc[0][jj] = fmaf(kc0, v8[jj], Cc[0][jj]);
                Cc[1][jj] = fmaf(kc1, v8[jj], Cc[1][jj]);
            }
        }
        __syncthreads();
    }

    float* kvb = kvp + (size_t)c * CSTRIDE + (size_t)g * TWO_D * D_DIM;
#pragma unroll
    for (int ii = 0; ii < 2; ++ii) {
        *(float4*)&kvb[(size_t)(i0 + ii) * D_DIM + j0] =
            make_float4(S[ii][0], S[ii][1], S[ii][2], S[ii][3]);
        *(float4*)&kvb[(size_t)(i0 + ii) * D_DIM + j0 + 4] =
            make_float4(S[ii][4], S[ii][5], S[ii][6], S[ii][7]);
        *(float4*)&kvb[(size_t)(64 + i0 + ii) * D_DIM + j0] =
            make_float4(Cc[ii][0], Cc[ii][1], Cc[ii][2], Cc[ii][3]);
        *(float4*)&kvb[(size_t)(64 + i0 + ii) * D_DIM + j0 + 4] =
            make_float4(Cc[ii][4], Cc[ii][5], Cc[ii][6], Cc[ii][7]);
    }
    if (gj == 0) {
        float* ksb = kvp + (size_t)c * CSTRIDE + KV_ELEMS + (size_t)g * TWO_D;
        ksb[i0] = sk[0];
        ksb[i0 + 1] = sk[1];
        ksb[64 + i0] = ck[0];
        ksb[64 + i0 + 1] = ck[1];
    }
}

// ---------------------------------------------------------------------------
// attn: head-major Q in; reduces kvp chunks inline; bf16 hi/lo (L,N,E) out.
// ---------------------------------------------------------------------------
__global__ __launch_bounds__(256) void attn_kernel(const float* __restrict__ Qh,
                                                   const float* __restrict__ kvp,
                                                   ushort* __restrict__ attnHi,
                                                   ushort* __restrict__ attnLo) {
    const int g = blockIdx.x;
    const int lt = blockIdx.y;
    const int nb = g >> 4, hh = g & 15;
    const int t = threadIdx.x;

    __shared__ float kvs[TWO_D][64];
    __shared__ float qT[TWO_D][64];
    __shared__ float sTab[64], cTab[64], ksS[TWO_D], pz[64][4], zs[64];

    {
        const float4* kv4 = (const float4*)(kvp + (size_t)g * TWO_D * D_DIM);
        const size_t cs4 = CSTRIDE / 4;
        float4* kvs4 = (float4*)&kvs[0][0];
        for (int s = t; s < TWO_D * D_DIM / 4; s += 256) {
            float4 a = kv4[s], b = kv4[s + cs4], c = kv4[s + 2 * cs4], d = kv4[s + 3 * cs4];
            kvs4[s] = make_float4(a.x + b.x + c.x + d.x, a.y + b.y + c.y + d.y,
                                  a.z + b.z + c.z + d.z, a.w + b.w + c.w + d.w);
        }
    }
    if (t < TWO_D) {
        const size_t o = KV_ELEMS + (size_t)g * TWO_D + t;
        ksS[t] = kvp[o] + kvp[o + CSTRIDE] + kvp[o + 2 * (size_t)CSTRIDE] + kvp[o + 3 * (size_t)CSTRIDE];
    }

    const int lbase = lt * 64;
    if (t < 64) {
        const float ang = 1.57079632679489662f * (float)(lbase + t + 1) / (float)L_DIM;
        sTab[t] = sinf(ang);
        cTab[t] = cosf(ang);
    }

    const int lq = t >> 2;
    const int dq = (t & 3) * 16;
    float qv[16];
    {
        const float* qrow = Qh + ((size_t)g * L_DIM + lbase + lq) * D_DIM + dq;
        *(float4*)&qv[0] = *(const float4*)&qrow[0];
        *(float4*)&qv[4] = *(const float4*)&qrow[4];
        *(float4*)&qv[8] = *(const float4*)&qrow[8];
        *(float4*)&qv[12] = *(const float4*)&qrow[12];
    }
    __syncthreads();

    {
        const float sl = sTab[lq], cl = cTab[lq];
#pragma unroll
        for (int jj = 0; jj < 16; ++jj) {
            qT[dq + jj][lq] = qv[jj] * sl;
            qT[64 + dq + jj][lq] = qv[jj] * cl;
        }
    }
    __syncthreads();

    {
        const int lz = t >> 2, qz = t & 3;
        float p = 0.f;
#pragma unroll
        for (int i = 0; i < 32; ++i) p = fmaf(qT[qz * 32 + i][lz], ksS[qz * 32 + i], p);
        pz[lz][qz] = p;
    }
    __syncthreads();
    if (t < 64) {
        const float s = pz[t][0] + pz[t][1] + pz[t][2] + pz[t][3];
        zs[t] = 1.0f / fmaxf(s, 1e-6f);
    }
    __syncthreads();

    const int ml = (t >> 4) * 4;
    const int nd = (t & 15) * 4;
    float acc[4][4];
#pragma unroll
    for (int i = 0; i < 4; ++i)
#pragma unroll
        for (int jj = 0; jj < 4; ++jj) acc[i][jj] = 0.f;

    for (int i = 0; i < TWO_D; ++i) {
        float4 a = *(float4*)&qT[i][ml];
        float4 b = *(float4*)&kvs[i][nd];
        acc[0][0] = fmaf(a.x, b.x, acc[0][0]); acc[0][1] = fmaf(a.x, b.y, acc[0][1]);
        acc[0][2] = fmaf(a.x, b.z, acc[0][2]); acc[0][3] = fmaf(a.x, b.w, acc[0][3]);
        acc[1][0] = fmaf(a.y, b.x, acc[1][0]); acc[1][1] = fmaf(a.y, b.y, acc[1][1]);
        acc[1][2] = fmaf(a.y, b.z, acc[1][2]); acc[1][3] = fmaf(a.y, b.w, acc[1][3]);
        acc[2][0] = fmaf(a.z, b.x, acc[2][0]); acc[2][1] = fmaf(a.z, b.y, acc[2][1]);
        acc[2][2] = fmaf(a.z, b.z, acc[2][2]); acc[2][3] = fmaf(a.z, b.w, acc[2][3]);
        acc[3][0] = fmaf(a.w, b.x, acc[3][0]); acc[3][1] = fmaf(a.w, b.y, acc[3][1]);
        acc[3][2] = fmaf(a.w, b.z, acc[3][2]); acc[3][3] = fmaf(a.w, b.w, acc[3][3]);
    }

#pragma unroll
    for (int r = 0; r < 4; ++r) {
        const float z = zs[ml + r];
        const float o0 = acc[r][0] * z, o1 = acc[r][1] * z;
        const float o2 = acc[r][2] * z, o3 = acc[r][3] * z;
        ushort4 hv, lv;
        hv.x = f2bf(o0); lv.x = f2bf(o0 - bf2f(hv.x));
        hv.y = f2bf(o1); lv.y = f2bf(o1 - bf2f(hv.y));
        hv.z = f2bf(o2); lv.z = f2bf(o2 - bf2f(hv.z));
        hv.w = f2bf(o3); lv.w = f2bf(o3 - bf2f(hv.w));
        const size_t base = (size_t)((lbase + ml + r) * N_DIM + nb) * E_DIM + hh * 64 + nd;
        *(ushort4*)&attnHi[base] = hv;
        *(ushort4*)&attnLo[base] = lv;
    }
}

// ---------------------------------------------------------------------------
extern "C" void kernel_launch(void* const* d_in, const int* in_sizes, int n_in,
                              void* d_out, int out_size, void* d_ws, size_t ws_size,
                              hipStream_t stream) {
    const float* X = (const float*)d_in[0];
    const float* Wq = (const float*)d_in[1];
    const float* Wk = (const float*)d_in[2];
    const float* Wv = (const float*)d_in[3];
    const float* Wo = (const float*)d_in[4];
    float* out = (float*)d_out;

    char* ws = (char*)d_ws;
    ushort* Xhi = (ushort*)(ws + 0);            // 32 MiB (later attnHi)
    ushort* Xlo = (ushort*)(ws + 33554432);     // 32 MiB (later attnLo)
    ushort* Whi = (ushort*)(ws + 67108864);     // 4 x 2 MiB (q,k,v,o)
    ushort* Wlo = (ushort*)(ws + 75497472);     // 4 x 2 MiB
    float* kvp  = (float*)(ws + 83886080);      // CH x 4.06 MiB
    float* bufA = (float*)(ws + 100925440);     // 64 MiB (Vh)
    // peak 160.25 MiB (same plan as round 3, proven)

    float* Kh = out;   // d_out doubles as scratch (Kh, then Qh, then output)
    float* Vh = bufA;
    float* Qh = out;

    const size_t WMAT = (size_t)E_DIM * E_DIM;

    split_fp32<<<2048, 256, 0, stream>>>(X, Xhi, Xlo, M_DIM * E_DIM / 4);
    split_w4<<<dim3(64, 4), 256, 0, stream>>>(Wq, Wk, Wv, Wo, Whi, Wlo);

    // fused K|V projection: B = [Wk; Wv] (2048 rows) -> Kh(relu), Vh
    // grid = 128 M-tiles x 8 N-tiles = 1024
    gemm3<2, 8><<<1024, 512, 0, stream>>>(Xhi, Xlo, Whi + 1 * WMAT, Wlo + 1 * WMAT, Kh, Vh);

    // kv partials (reduced inside attn)
    kv_partial<<<dim3(NHEADS, CH), 256, 0, stream>>>(Kh, Vh, kvp);

    // Q projection (Kh dead -> reuse d_out); grid = 128 x 4 = 512
    gemm3<1, 4><<<512, 512, 0, stream>>>(Xhi, Xlo, Whi + 0 * WMAT, Wlo + 0 * WMAT, Qh, nullptr);

    // attn -> bf16 hi/lo into X region (X dead)
    attn_kernel<<<dim3(NHEADS, L_DIM / 64), 256, 0, stream>>>(Qh, kvp, Xhi, Xlo);

    // out = attn Wo^T; grid = 128 x 4 = 512
    gemm3<0, 4><<<512, 512, 0, stream>>>(Xhi, Xlo, Whi + 3 * WMAT, Wlo + 3 * WMAT, out, nullptr);
}

// Round 7
// 537.960 us; speedup vs baseline: 3.2902x; 1.0682x over previous
//
#include <hip/hip_runtime.h>
#include <math.h>

#define L_DIM 2048
#define N_DIM 8
#define E_DIM 1024
#define H_DIM 16
#define D_DIM 64
#define M_DIM (L_DIM * N_DIM)     // 16384
#define NHEADS (N_DIM * H_DIM)    // 128
#define TWO_D 128
#define K_DIM 1024
#define CH 4                      // L-chunks for kv partials
#define LCH (L_DIM / CH)          // 512

#define KV_ELEMS (NHEADS * TWO_D * D_DIM)   // 1048576
#define KS_ELEMS (NHEADS * TWO_D)           // 16384
#define CSTRIDE (KV_ELEMS + KS_ELEMS)       // 1064960 floats per chunk

typedef __attribute__((ext_vector_type(8))) __bf16 bf16x8;
typedef __attribute__((ext_vector_type(4))) float f32x4;

__device__ __forceinline__ ushort f2bf(float x) {
    union { float f; unsigned u; } a; a.f = x;
    unsigned r = a.u + 0x7fffu + ((a.u >> 16) & 1u);
    return (ushort)(r >> 16);
}
__device__ __forceinline__ float bf2f(ushort h) {
    union { unsigned u; float f; } a; a.u = ((unsigned)h) << 16;
    return a.f;
}

__device__ __forceinline__ void gload_lds16(const void* g, void* l) {
    __builtin_amdgcn_global_load_lds((const __attribute__((address_space(1))) void*)g,
                                     (__attribute__((address_space(3))) void*)l, 16, 0, 0);
}

// ---------------------------------------------------------------------------
// split fp32 -> bf16 hi + lo
// ---------------------------------------------------------------------------
__global__ __launch_bounds__(256) void split_fp32(const float* __restrict__ in,
                                                  ushort* __restrict__ hi,
                                                  ushort* __restrict__ lo, int n4) {
    int i = blockIdx.x * 256 + threadIdx.x;
    const int stride = gridDim.x * 256;
    for (; i < n4; i += stride) {
        float4 v = ((const float4*)in)[i];
        ushort h0 = f2bf(v.x), h1 = f2bf(v.y), h2 = f2bf(v.z), h3 = f2bf(v.w);
        ushort l0 = f2bf(v.x - bf2f(h0)), l1 = f2bf(v.y - bf2f(h1));
        ushort l2 = f2bf(v.z - bf2f(h2)), l3 = f2bf(v.w - bf2f(h3));
        ((ushort4*)hi)[i] = make_ushort4(h0, h1, h2, h3);
        ((ushort4*)lo)[i] = make_ushort4(l0, l1, l2, l3);
    }
}

__global__ __launch_bounds__(256) void split_w4(const float* __restrict__ w0,
                                                const float* __restrict__ w1,
                                                const float* __restrict__ w2,
                                                const float* __restrict__ w3,
                                                ushort* __restrict__ hi,
                                                ushort* __restrict__ lo) {
    const int midx = blockIdx.y;
    const float* src = (midx == 0) ? w0 : (midx == 1) ? w1 : (midx == 2) ? w2 : w3;
    hi += (size_t)midx * E_DIM * E_DIM;
    lo += (size_t)midx * E_DIM * E_DIM;
    const int n4 = E_DIM * E_DIM / 4;
    int i = blockIdx.x * 256 + threadIdx.x;
    const int stride = gridDim.x * 256;
    for (; i < n4; i += stride) {
        float4 v = ((const float4*)src)[i];
        ushort h0 = f2bf(v.x), h1 = f2bf(v.y), h2 = f2bf(v.z), h3 = f2bf(v.w);
        ushort l0 = f2bf(v.x - bf2f(h0)), l1 = f2bf(v.y - bf2f(h1));
        ushort l2 = f2bf(v.z - bf2f(h2)), l3 = f2bf(v.w - bf2f(h3));
        ((ushort4*)hi)[i] = make_ushort4(h0, h1, h2, h3);
        ((ushort4*)lo)[i] = make_ushort4(l0, l1, l2, l3);
    }
}

// ---------------------------------------------------------------------------
// split-bf16 MFMA GEMM-NT, 256x256 tile, BK=32, 8 waves (2M x 4N, 128x64/wave).
// PROVEN round-3 sync structure: STAGE(next) -> compute(cur) -> __syncthreads.
// 2 LDS buffers x 64 KiB. 3 MFMAs per (m,n,k): hi*hi + hi*lo + lo*hi.
// Grid MUST be 64 * NBS blocks (64 M-tiles x NBS N-tiles of 256).
// OUTMODE 0: row-major fp32; 1: head-major+relu (Q); 2: fused K|V head-major.
// ---------------------------------------------------------------------------
template <int OUTMODE, int NBS>
__global__ __launch_bounds__(512, 2) void gemm2(const ushort* __restrict__ Ahi,
                                                const ushort* __restrict__ Alo,
                                                const ushort* __restrict__ Bhi,
                                                const ushort* __restrict__ Blo,
                                                float* __restrict__ C,
                                                float* __restrict__ C2) {
    // buffer (ushorts): Ah[0,8192) Al[8192,16384) Bh[16384,24576) Bl[24576,32768)
    __shared__ ushort smem[2][32768];  // 128 KiB

    const int t = threadIdx.x;
    const int wid = t >> 6;
    const int lane = t & 63;

    // T1: XCD-grouped decomposition. grid = 64*NBS, 8*NBS blocks per XCD.
    const int x = blockIdx.x;
    const int cxcd = x & 7;
    const int j = x >> 3;                 // 0 .. 8*NBS-1
    const int mb = cxcd * 8 + j / NBS;    // 0..63
    const int nb = j % NBS;
    const int m0 = mb * 256, n0 = nb * 256;

    // ---- staging source offsets (inverse-swizzled; LDS dest linear) ----
    const int srow = t >> 2;                  // 0..127
    const int sch = t & 3;
    const int gch = sch ^ ((srow >> 1) & 3);  // invariant under row+128
    const size_t aOff = (size_t)(m0 + srow) * K_DIM + gch * 8;
    const size_t bOff = (size_t)(n0 + srow) * K_DIM + gch * 8;
    const size_t H128 = (size_t)128 * K_DIM;

#define STAGE(b, kt1)                                             \
    do {                                                          \
        const size_t kc_ = (size_t)(kt1) * 32;                    \
        ushort* d = (ushort*)&smem[b][0] + wid * 512;             \
        gload_lds16(Ahi + aOff + kc_, d);                         \
        gload_lds16(Ahi + aOff + H128 + kc_, d + 4096);           \
        gload_lds16(Alo + aOff + kc_, d + 8192);                  \
        gload_lds16(Alo + aOff + H128 + kc_, d + 12288);          \
        gload_lds16(Bhi + bOff + kc_, d + 16384);                 \
        gload_lds16(Bhi + bOff + H128 + kc_, d + 20480);          \
        gload_lds16(Blo + bOff + kc_, d + 24576);                 \
        gload_lds16(Blo + bOff + H128 + kc_, d + 28672);          \
    } while (0)

    // ---- fragment read offsets (swizzled), per-wave 128(M) x 64(N) ----
    const int wm = wid >> 2;       // 0..1 -> M half (stride 128)
    const int wn = wid & 3;        // 0..3 -> N quarter (stride 64)
    const int lr = lane & 15;
    const int kc = lane >> 4;
    int aoff[8], boff[4];
#pragma unroll
    for (int m = 0; m < 8; ++m) {
        const int r = wm * 128 + m * 16 + lr;
        aoff[m] = r * 32 + ((kc ^ ((r >> 1) & 3)) << 3);
    }
#pragma unroll
    for (int n = 0; n < 4; ++n) {
        const int r = wn * 64 + n * 16 + lr;
        boff[n] = r * 32 + ((kc ^ ((r >> 1) & 3)) << 3);
    }

    f32x4 acc[8][4];
    const f32x4 zv = {0.f, 0.f, 0.f, 0.f};
#pragma unroll
    for (int m = 0; m < 8; ++m)
#pragma unroll
        for (int n = 0; n < 4; ++n) acc[m][n] = zv;

    const int NK = K_DIM / 32;  // 32

    STAGE(0, 0);
    __syncthreads();

#pragma unroll 1
    for (int kt = 0; kt < NK; ++kt) {
        const int cb = kt & 1;
        if (kt + 1 < NK) STAGE(cb ^ 1, kt + 1);

        const ushort* bb = smem[cb];
        bf16x8 bh[4], bl[4];
#pragma unroll
        for (int n = 0; n < 4; ++n) {
            bh[n] = *(const bf16x8*)&bb[16384 + boff[n]];
            bl[n] = *(const bf16x8*)&bb[24576 + boff[n]];
        }
#pragma unroll
        for (int m = 0; m < 8; ++m) {
            const bf16x8 ah = *(const bf16x8*)&bb[aoff[m]];
            const bf16x8 al = *(const bf16x8*)&bb[8192 + aoff[m]];
#pragma unroll
            for (int n = 0; n < 4; ++n) {
                acc[m][n] = __builtin_amdgcn_mfma_f32_16x16x32_bf16(ah, bh[n], acc[m][n], 0, 0, 0);
                acc[m][n] = __builtin_amdgcn_mfma_f32_16x16x32_bf16(ah, bl[n], acc[m][n], 0, 0, 0);
                acc[m][n] = __builtin_amdgcn_mfma_f32_16x16x32_bf16(al, bh[n], acc[m][n], 0, 0, 0);
            }
        }
        __syncthreads();
    }

    // ---- epilogue: C/D layout col=lane&15, row=(lane>>4)*4+q ----
    const int erow = (lane >> 4) * 4;
    const int ecol = lane & 15;
#pragma unroll
    for (int m = 0; m < 8; ++m) {
        const int grb = m0 + wm * 128 + m * 16 + erow;
#pragma unroll
        for (int n = 0; n < 4; ++n) {
            const int gc = n0 + wn * 64 + n * 16 + ecol;
            f32x4 v = acc[m][n];
#pragma unroll
            for (int q = 0; q < 4; ++q) {
                const int gr = grb + q;
                float val = v[q];
                if constexpr (OUTMODE == 0) {
                    C[(size_t)gr * E_DIM + gc] = val;
                } else if constexpr (OUTMODE == 1) {
                    val = fmaxf(val, 0.f);
                    const int hh = gc >> 6, d = gc & 63;
                    C[((size_t)((gr & 7) * 16 + hh) * L_DIM + (gr >> 3)) * D_DIM + d] = val;
                } else {
                    const int mat = gc >> 10;  // 0 = K (relu), 1 = V
                    const int col = gc & 1023;
                    if (mat == 0) val = fmaxf(val, 0.f);
                    const int hh = col >> 6, d = col & 63;
                    float* dstc = mat ? C2 : C;
                    dstc[((size_t)((gr & 7) * 16 + hh) * L_DIM + (gr >> 3)) * D_DIM + d] = val;
                }
            }
        }
    }
#undef STAGE
}

// ---------------------------------------------------------------------------
// kv partials from head-major K/V (contiguous streams, no atomics)
// ---------------------------------------------------------------------------
__global__ __launch_bounds__(256) void kv_partial(const float* __restrict__ Kh,
                                                  const float* __restrict__ Vh,
                                                  float* __restrict__ kvp) {
    const int g = blockIdx.x;
    const int c = blockIdx.y;
    const int t = threadIdx.x;

    __shared__ float Kt[32][64];
    __shared__ float Vt[32][64];
    __shared__ float sT[32], cT[32];

    const int gi = t >> 3;
    const int gj = t & 7;
    const int i0 = gi * 2, j0 = gj * 8;

    float S[2][8], Cc[2][8];
#pragma unroll
    for (int i = 0; i < 2; ++i)
#pragma unroll
        for (int jj = 0; jj < 8; ++jj) { S[i][jj] = 0.f; Cc[i][jj] = 0.f; }
    float sk[2] = {0.f, 0.f}, ck[2] = {0.f, 0.f};

    for (int lt = 0; lt < LCH; lt += 32) {
        const int lbase = c * LCH + lt;
        const float4* ks = (const float4*)&Kh[((size_t)g * L_DIM + lbase) * D_DIM];
        const float4* vs = (const float4*)&Vh[((size_t)g * L_DIM + lbase) * D_DIM];
        ((float4*)&Kt[0][0])[t] = ks[t];
        ((float4*)&Kt[0][0])[t + 256] = ks[t + 256];
        ((float4*)&Vt[0][0])[t] = vs[t];
        ((float4*)&Vt[0][0])[t + 256] = vs[t + 256];
        if (t < 32) {
            const float ang = 1.57079632679489662f * (float)(lbase + t + 1) / (float)L_DIM;
            sT[t] = sinf(ang);
            cT[t] = cosf(ang);
        }
        __syncthreads();
#pragma unroll 4
        for (int lr = 0; lr < 32; ++lr) {
            const float sl = sT[lr], cl = cT[lr];
            const float k0v = Kt[lr][i0], k1v = Kt[lr][i0 + 1];
            const float ks0 = k0v * sl, ks1 = k1v * sl;
            const float kc0 = k0v * cl, kc1 = k1v * cl;
            sk[0] += ks0; sk[1] += ks1; ck[0] += kc0; ck[1] += kc1;
            float v8[8];
            *(float4*)&v8[0] = *(float4*)&Vt[lr][j0];
            *(float4*)&v8[4] = *(float4*)&Vt[lr][j0 + 4];
#pragma unroll
            for (int jj = 0; jj < 8; ++jj) {
                S[0][jj] = fmaf(ks0, v8[jj], S[0][jj]);
                S[1][jj] = fmaf(ks1, v8[jj], S[1][jj]);
                Cc[0][jj] = fmaf(kc0, v8[jj], Cc[0][jj]);
                Cc[1][jj] = fmaf(kc1, v8[jj], Cc[1][jj]);
            }
        }
        __syncthreads();
    }

    float* kvb = kvp + (size_t)c * CSTRIDE + (size_t)g * TWO_D * D_DIM;
#pragma unroll
    for (int ii = 0; ii < 2; ++ii) {
        *(float4*)&kvb[(size_t)(i0 + ii) * D_DIM + j0] =
            make_float4(S[ii][0], S[ii][1], S[ii][2], S[ii][3]);
        *(float4*)&kvb[(size_t)(i0 + ii) * D_DIM + j0 + 4] =
            make_float4(S[ii][4], S[ii][5], S[ii][6], S[ii][7]);
        *(float4*)&kvb[(size_t)(64 + i0 + ii) * D_DIM + j0] =
            make_float4(Cc[ii][0], Cc[ii][1], Cc[ii][2], Cc[ii][3]);
        *(float4*)&kvb[(size_t)(64 + i0 + ii) * D_DIM + j0 + 4] =
            make_float4(Cc[ii][4], Cc[ii][5], Cc[ii][6], Cc[ii][7]);
    }
    if (gj == 0) {
        float* ksb = kvp + (size_t)c * CSTRIDE + KV_ELEMS + (size_t)g * TWO_D;
        ksb[i0] = sk[0];
        ksb[i0 + 1] = sk[1];
        ksb[64 + i0] = ck[0];
        ksb[64 + i0 + 1] = ck[1];
    }
}

// ---------------------------------------------------------------------------
// attn: head-major Q in; reduces kvp chunks inline; bf16 hi/lo (L,N,E) out.
// ---------------------------------------------------------------------------
__global__ __launch_bounds__(256) void attn_kernel(const float* __restrict__ Qh,
                                                   const float* __restrict__ kvp,
                                                   ushort* __restrict__ attnHi,
                                                   ushort* __restrict__ attnLo) {
    const int g = blockIdx.x;
    const int lt = blockIdx.y;
    const int nb = g >> 4, hh = g & 15;
    const int t = threadIdx.x;

    __shared__ float kvs[TWO_D][64];
    __shared__ float qT[TWO_D][64];
    __shared__ float sTab[64], cTab[64], ksS[TWO_D], pz[64][4], zs[64];

    {
        const float4* kv4 = (const float4*)(kvp + (size_t)g * TWO_D * D_DIM);
        const size_t cs4 = CSTRIDE / 4;
        float4* kvs4 = (float4*)&kvs[0][0];
        for (int s = t; s < TWO_D * D_DIM / 4; s += 256) {
            float4 a = kv4[s], b = kv4[s + cs4], c = kv4[s + 2 * cs4], d = kv4[s + 3 * cs4];
            kvs4[s] = make_float4(a.x + b.x + c.x + d.x, a.y + b.y + c.y + d.y,
                                  a.z + b.z + c.z + d.z, a.w + b.w + c.w + d.w);
        }
    }
    if (t < TWO_D) {
        const size_t o = KV_ELEMS + (size_t)g * TWO_D + t;
        ksS[t] = kvp[o] + kvp[o + CSTRIDE] + kvp[o + 2 * (size_t)CSTRIDE] + kvp[o + 3 * (size_t)CSTRIDE];
    }

    const int lbase = lt * 64;
    if (t < 64) {
        const float ang = 1.57079632679489662f * (float)(lbase + t + 1) / (float)L_DIM;
        sTab[t] = sinf(ang);
        cTab[t] = cosf(ang);
    }

    const int lq = t >> 2;
    const int dq = (t & 3) * 16;
    float qv[16];
    {
        const float* qrow = Qh + ((size_t)g * L_DIM + lbase + lq) * D_DIM + dq;
        *(float4*)&qv[0] = *(const float4*)&qrow[0];
        *(float4*)&qv[4] = *(const float4*)&qrow[4];
        *(float4*)&qv[8] = *(const float4*)&qrow[8];
        *(float4*)&qv[12] = *(const float4*)&qrow[12];
    }
    __syncthreads();

    {
        const float sl = sTab[lq], cl = cTab[lq];
#pragma unroll
        for (int jj = 0; jj < 16; ++jj) {
            qT[dq + jj][lq] = qv[jj] * sl;
            qT[64 + dq + jj][lq] = qv[jj] * cl;
        }
    }
    __syncthreads();

    {
        const int lz = t >> 2, qz = t & 3;
        float p = 0.f;
#pragma unroll
        for (int i = 0; i < 32; ++i) p = fmaf(qT[qz * 32 + i][lz], ksS[qz * 32 + i], p);
        pz[lz][qz] = p;
    }
    __syncthreads();
    if (t < 64) {
        const float s = pz[t][0] + pz[t][1] + pz[t][2] + pz[t][3];
        zs[t] = 1.0f / fmaxf(s, 1e-6f);
    }
    __syncthreads();

    const int ml = (t >> 4) * 4;
    const int nd = (t & 15) * 4;
    float acc[4][4];
#pragma unroll
    for (int i = 0; i < 4; ++i)
#pragma unroll
        for (int jj = 0; jj < 4; ++jj) acc[i][jj] = 0.f;

    for (int i = 0; i < TWO_D; ++i) {
        float4 a = *(float4*)&qT[i][ml];
        float4 b = *(float4*)&kvs[i][nd];
        acc[0][0] = fmaf(a.x, b.x, acc[0][0]); acc[0][1] = fmaf(a.x, b.y, acc[0][1]);
        acc[0][2] = fmaf(a.x, b.z, acc[0][2]); acc[0][3] = fmaf(a.x, b.w, acc[0][3]);
        acc[1][0] = fmaf(a.y, b.x, acc[1][0]); acc[1][1] = fmaf(a.y, b.y, acc[1][1]);
        acc[1][2] = fmaf(a.y, b.z, acc[1][2]); acc[1][3] = fmaf(a.y, b.w, acc[1][3]);
        acc[2][0] = fmaf(a.z, b.x, acc[2][0]); acc[2][1] = fmaf(a.z, b.y, acc[2][1]);
        acc[2][2] = fmaf(a.z, b.z, acc[2][2]); acc[2][3] = fmaf(a.z, b.w, acc[2][3]);
        acc[3][0] = fmaf(a.w, b.x, acc[3][0]); acc[3][1] = fmaf(a.w, b.y, acc[3][1]);
        acc[3][2] = fmaf(a.w, b.z, acc[3][2]); acc[3][3] = fmaf(a.w, b.w, acc[3][3]);
    }

#pragma unroll
    for (int r = 0; r < 4; ++r) {
        const float z = zs[ml + r];
        const float o0 = acc[r][0] * z, o1 = acc[r][1] * z;
        const float o2 = acc[r][2] * z, o3 = acc[r][3] * z;
        ushort4 hv, lv;
        hv.x = f2bf(o0); lv.x = f2bf(o0 - bf2f(hv.x));
        hv.y = f2bf(o1); lv.y = f2bf(o1 - bf2f(hv.y));
        hv.z = f2bf(o2); lv.z = f2bf(o2 - bf2f(hv.z));
        hv.w = f2bf(o3); lv.w = f2bf(o3 - bf2f(hv.w));
        const size_t base = (size_t)((lbase + ml + r) * N_DIM + nb) * E_DIM + hh * 64 + nd;
        *(ushort4*)&attnHi[base] = hv;
        *(ushort4*)&attnLo[base] = lv;
    }
}

// ---------------------------------------------------------------------------
extern "C" void kernel_launch(void* const* d_in, const int* in_sizes, int n_in,
                              void* d_out, int out_size, void* d_ws, size_t ws_size,
                              hipStream_t stream) {
    const float* X = (const float*)d_in[0];
    const float* Wq = (const float*)d_in[1];
    const float* Wk = (const float*)d_in[2];
    const float* Wv = (const float*)d_in[3];
    const float* Wo = (const float*)d_in[4];
    float* out = (float*)d_out;

    char* ws = (char*)d_ws;
    ushort* Xhi = (ushort*)(ws + 0);            // 32 MiB (later attnHi)
    ushort* Xlo = (ushort*)(ws + 33554432);     // 32 MiB (later attnLo)
    ushort* Whi = (ushort*)(ws + 67108864);     // 4 x 2 MiB (q,k,v,o)
    ushort* Wlo = (ushort*)(ws + 75497472);     // 4 x 2 MiB
    float* kvp  = (float*)(ws + 83886080);      // CH x 4.06 MiB
    float* bufA = (float*)(ws + 100925440);     // 64 MiB (Vh)
    // peak 160.25 MiB (proven plan)

    float* Kh = out;   // d_out doubles as scratch (Kh, then Qh, then output)
    float* Vh = bufA;
    float* Qh = out;

    const size_t WMAT = (size_t)E_DIM * E_DIM;

    split_fp32<<<2048, 256, 0, stream>>>(X, Xhi, Xlo, M_DIM * E_DIM / 4);
    split_w4<<<dim3(64, 4), 256, 0, stream>>>(Wq, Wk, Wv, Wo, Whi, Wlo);

    // fused K|V projection: B = [Wk; Wv] (2048 rows) -> Kh(relu), Vh
    // grid = 64 M-tiles x 8 N-tiles = 512
    gemm2<2, 8><<<512, 512, 0, stream>>>(Xhi, Xlo, Whi + 1 * WMAT, Wlo + 1 * WMAT, Kh, Vh);

    // kv partials (reduced inside attn)
    kv_partial<<<dim3(NHEADS, CH), 256, 0, stream>>>(Kh, Vh, kvp);

    // Q projection (Kh dead -> reuse d_out); grid = 64 x 4 = 256
    gemm2<1, 4><<<256, 512, 0, stream>>>(Xhi, Xlo, Whi + 0 * WMAT, Wlo + 0 * WMAT, Qh, nullptr);

    // attn -> bf16 hi/lo into X region (X dead)
    attn_kernel<<<dim3(NHEADS, L_DIM / 64), 256, 0, stream>>>(Qh, kvp, Xhi, Xlo);

    // out = attn Wo^T; grid = 64 x 4 = 256
    gemm2<0, 4><<<256, 512, 0, stream>>>(Xhi, Xlo, Whi + 3 * WMAT, Wlo + 3 * WMAT, out, nullptr);
}